// Round 12
// baseline (208.578 us; speedup 1.0000x reference)
//
#include <hip/hip_runtime.h>
#include <hip/hip_bf16.h>

#define D_MODEL 1024
#define D_INNER 2048
#define NPROJ   4096   /* 2*D_INNER */
#define D_STATE 16
#define DT_RANK 128
#define XPJ_N   160    /* DT_RANK + 2*D_STATE */
#define SEQLEN  1024
#define BATCH   2
#define NTOK    2048   /* BATCH*SEQLEN */
#define CHUNK   32
#define NCHUNK  (SEQLEN / CHUNK)   /* 32 */
#define LOG2_NCHUNK 5
#define SPLITK  8      /* gemm4 split */
#define OP_SPLITK 4    /* out_proj split */

typedef short short8 __attribute__((ext_vector_type(8)));
typedef float f32x4 __attribute__((ext_vector_type(4)));

__device__ __forceinline__ float sigmoidf_(float x) { return 1.f / (1.f + __expf(-x)); }
__device__ __forceinline__ ushort f2bf_bits(float f) {
    __hip_bfloat16 h = __float2bfloat16(f);
    return *(ushort*)&h;
}
__device__ __forceinline__ float bf2f(ushort u) {
    union { unsigned int i; float f; } v;
    v.i = ((unsigned int)u) << 16;
    return v.f;
}
#define LOG2E 1.44269504088896f

// ---------------- LayerNorm → bf16 output ----------------
__global__ __launch_bounds__(256) void ln_kernel(const float* __restrict__ x,
                                                 const float* __restrict__ g,
                                                 const float* __restrict__ be,
                                                 ushort* __restrict__ hb)
{
    int row = blockIdx.x;
    const float4* xr = (const float4*)(x + (long)row * D_MODEL);
    float4 v = xr[threadIdx.x];
    float s1 = v.x + v.y + v.z + v.w;
    float s2 = v.x*v.x + v.y*v.y + v.z*v.z + v.w*v.w;
    for (int off = 32; off >= 1; off >>= 1) {
        s1 += __shfl_down(s1, off);
        s2 += __shfl_down(s2, off);
    }
    __shared__ float red[8];
    int wid = threadIdx.x >> 6;
    if ((threadIdx.x & 63) == 0) { red[wid] = s1; red[4 + wid] = s2; }
    __syncthreads();
    float mu  = (red[0] + red[1] + red[2] + red[3]) * (1.f / D_MODEL);
    float ex2 = (red[4] + red[5] + red[6] + red[7]) * (1.f / D_MODEL);
    float inv = rsqrtf(ex2 - mu * mu + 1e-5f);
    float4 g4 = ((const float4*)g)[threadIdx.x];
    float4 b4 = ((const float4*)be)[threadIdx.x];
    ushort4 o;
    o.x = f2bf_bits((v.x - mu) * inv * g4.x + b4.x);
    o.y = f2bf_bits((v.y - mu) * inv * g4.y + b4.y);
    o.z = f2bf_bits((v.z - mu) * inv * g4.z + b4.z);
    o.w = f2bf_bits((v.w - mu) * inv * g4.w + b4.w);
    *(ushort4*)(hb + (long)row * D_MODEL + threadIdx.x * 4) = o;
}

// ---------------- f32 [R][C] → bf16 [C][R] transpose (guarded) ----------------
__global__ __launch_bounds__(256) void transpose_bf16_kernel(const float* __restrict__ in,
                                                             ushort* __restrict__ out,
                                                             int R, int C)
{
    __shared__ float tile[64][65];
    int c0 = blockIdx.x * 64, r0 = blockIdx.y * 64;
    #pragma unroll
    for (int i = 0; i < 16; ++i) {
        int idx = threadIdx.x + i * 256;
        int r = idx >> 6, c = idx & 63;
        tile[r][c] = (r0 + r < R && c0 + c < C) ? in[(long)(r0 + r) * C + (c0 + c)] : 0.f;
    }
    __syncthreads();
    #pragma unroll
    for (int i = 0; i < 16; ++i) {
        int idx = threadIdx.x + i * 256;
        int cc = idx >> 6, rr = idx & 63;
        if (c0 + cc < C && r0 + rr < R)
            out[(long)(c0 + cc) * R + (r0 + rr)] = f2bf_bits(tile[rr][cc]);
    }
}

// ---------------- bf16 MFMA GEMM 128x128: C = A[M,K(lda)] * Bt[N,K(ldb)]^T -----------
template <int EPI, int OBF>
__global__ __launch_bounds__(256) void gemm_mfma_kernel(const ushort* __restrict__ A,
                                                        const ushort* __restrict__ Bt,
                                                        const float* __restrict__ bias,
                                                        float* __restrict__ Cf,
                                                        ushort* __restrict__ Cb,
                                                        int M, int N, int K, int lda, int ldb)
{
    long zoff = (long)blockIdx.z;
    A  += zoff * K;
    Bt += zoff * K;
    if (OBF == 0) Cf += zoff * (long)M * N;
    __shared__ __align__(16) ushort Al[128 * 32];
    __shared__ __align__(16) ushort Bl[128 * 32];
    int tid = threadIdx.x;
    int lane = tid & 63;
    int w = tid >> 6, wr = w >> 1, wc = w & 1;
    int m0 = blockIdx.y * 128, n0 = blockIdx.x * 128;
    f32x4 acc[4][4];
    #pragma unroll
    for (int m = 0; m < 4; ++m)
        #pragma unroll
        for (int n = 0; n < 4; ++n) acc[m][n] = (f32x4){0.f, 0.f, 0.f, 0.f};
    int l15 = lane & 15, kq = lane >> 4;

    for (int k0 = 0; k0 < K; k0 += 32) {
        #pragma unroll
        for (int i = 0; i < 2; ++i) {
            int s = i * 256 + tid;
            int row = s >> 2, kg = s & 3;
            int kgl = kg ^ ((row >> 1) & 3);
            __builtin_amdgcn_global_load_lds(
                (const __attribute__((address_space(1))) void*)(A + (long)(m0 + row) * lda + k0 + kgl * 8),
                (__attribute__((address_space(3))) void*)(Al + s * 8), 16, 0, 0);
            __builtin_amdgcn_global_load_lds(
                (const __attribute__((address_space(1))) void*)(Bt + (long)(n0 + row) * ldb + k0 + kgl * 8),
                (__attribute__((address_space(3))) void*)(Bl + s * 8), 16, 0, 0);
        }
        __syncthreads();
        short8 af[4], bf[4];
        #pragma unroll
        for (int m = 0; m < 4; ++m) {
            int row = wr * 64 + m * 16 + l15;
            af[m] = *(const short8*)&Al[row * 32 + (kq ^ ((row >> 1) & 3)) * 8];
        }
        #pragma unroll
        for (int n = 0; n < 4; ++n) {
            int row = wc * 64 + n * 16 + l15;
            bf[n] = *(const short8*)&Bl[row * 32 + (kq ^ ((row >> 1) & 3)) * 8];
        }
        #pragma unroll
        for (int m = 0; m < 4; ++m)
            #pragma unroll
            for (int n = 0; n < 4; ++n)
                acc[m][n] = __builtin_amdgcn_mfma_f32_16x16x32_bf16(af[m], bf[n], acc[m][n], 0, 0, 0);
        __syncthreads();
    }
    #pragma unroll
    for (int m = 0; m < 4; ++m) {
        #pragma unroll
        for (int n = 0; n < 4; ++n) {
            #pragma unroll
            for (int r = 0; r < 4; ++r) {
                int row = m0 + wr * 64 + m * 16 + kq * 4 + r;
                int col = n0 + wc * 64 + n * 16 + l15;
                float v = acc[m][n][r];
                if (EPI == 1) {
                    v += bias[col];
                    v = (v > 20.f) ? v : log1pf(__expf(v));
                }
                if (OBF) Cb[(long)row * N + col] = f2bf_bits(v);
                else     Cf[(long)row * N + col] = v;
            }
        }
    }
}

// ---------------- bf16 MFMA GEMM 128x64 ----------------
template <int EPI, int OBF>
__global__ __launch_bounds__(256) void gemm_mfma64_kernel(const ushort* __restrict__ A,
                                                          const ushort* __restrict__ Bt,
                                                          const float* __restrict__ bias,
                                                          float* __restrict__ Cf,
                                                          ushort* __restrict__ Cb,
                                                          int M, int N, int K)
{
    __shared__ __align__(16) ushort Al[128 * 32];
    __shared__ __align__(16) ushort Bl[64 * 32];
    int tid = threadIdx.x;
    int lane = tid & 63;
    int w = tid >> 6, wr = w >> 1, wc = w & 1;
    int m0 = blockIdx.y * 128, n0 = blockIdx.x * 64;
    f32x4 acc[4][2];
    #pragma unroll
    for (int m = 0; m < 4; ++m)
        #pragma unroll
        for (int n = 0; n < 2; ++n) acc[m][n] = (f32x4){0.f, 0.f, 0.f, 0.f};
    int l15 = lane & 15, kq = lane >> 4;

    for (int k0 = 0; k0 < K; k0 += 32) {
        #pragma unroll
        for (int i = 0; i < 2; ++i) {
            int s = i * 256 + tid;
            int row = s >> 2, kg = s & 3;
            int kgl = kg ^ ((row >> 1) & 3);
            __builtin_amdgcn_global_load_lds(
                (const __attribute__((address_space(1))) void*)(A + (long)(m0 + row) * K + k0 + kgl * 8),
                (__attribute__((address_space(3))) void*)(Al + s * 8), 16, 0, 0);
        }
        {
            int s = tid;
            int row = s >> 2, kg = s & 3;
            int kgl = kg ^ ((row >> 1) & 3);
            __builtin_amdgcn_global_load_lds(
                (const __attribute__((address_space(1))) void*)(Bt + (long)(n0 + row) * K + k0 + kgl * 8),
                (__attribute__((address_space(3))) void*)(Bl + s * 8), 16, 0, 0);
        }
        __syncthreads();
        short8 af[4], bf[2];
        #pragma unroll
        for (int m = 0; m < 4; ++m) {
            int row = wr * 64 + m * 16 + l15;
            af[m] = *(const short8*)&Al[row * 32 + (kq ^ ((row >> 1) & 3)) * 8];
        }
        #pragma unroll
        for (int n = 0; n < 2; ++n) {
            int row = wc * 32 + n * 16 + l15;
            bf[n] = *(const short8*)&Bl[row * 32 + (kq ^ ((row >> 1) & 3)) * 8];
        }
        #pragma unroll
        for (int m = 0; m < 4; ++m)
            #pragma unroll
            for (int n = 0; n < 2; ++n)
                acc[m][n] = __builtin_amdgcn_mfma_f32_16x16x32_bf16(af[m], bf[n], acc[m][n], 0, 0, 0);
        __syncthreads();
    }
    #pragma unroll
    for (int m = 0; m < 4; ++m) {
        #pragma unroll
        for (int n = 0; n < 2; ++n) {
            #pragma unroll
            for (int r = 0; r < 4; ++r) {
                int row = m0 + wr * 64 + m * 16 + kq * 4 + r;
                int col = n0 + wc * 32 + n * 16 + l15;
                float v = acc[m][n][r];
                if (EPI == 1) {
                    v += bias[col];
                    v = (v > 20.f) ? v : log1pf(__expf(v));
                }
                if (OBF) Cb[(long)row * N + col] = f2bf_bits(v);
                else     Cf[(long)row * N + col] = v;
            }
        }
    }
}

// -------- out_proj split-K reduce: out = sum_k Ppart[k] + resid --------
__global__ __launch_bounds__(256) void reduce_out_kernel(const float* __restrict__ Ppart,
                                                         const float* __restrict__ resid,
                                                         float* __restrict__ out)
{
    long i = (long)blockIdx.x * 256 + threadIdx.x;
    const long STRIDE = (long)NTOK * D_MODEL / 4;
    float4 s = ((const float4*)Ppart)[i];
    #pragma unroll
    for (int k = 1; k < OP_SPLITK; ++k) {
        float4 p = ((const float4*)Ppart)[k * STRIDE + i];
        s.x += p.x; s.y += p.y; s.z += p.z; s.w += p.w;
    }
    float4 r = ((const float4*)resid)[i];
    s.x += r.x; s.y += r.y; s.z += r.z; s.w += r.w;
    ((float4*)out)[i] = s;
}

// -------- split-K bf16 MFMA GEMM for xpj --------
__global__ __launch_bounds__(256) void gemm4_mfma_kernel(const ushort* __restrict__ A,
                                                         const ushort* __restrict__ Bt,
                                                         float* __restrict__ Ppart,
                                                         int M, int K)
{
    __shared__ __align__(16) ushort Al[64 * 32];
    __shared__ __align__(16) ushort Bl[160 * 32];
    int tid = threadIdx.x;
    int lane = tid & 63;
    int w = tid >> 6, wr = w >> 1, wc = w & 1;
    int sk = blockIdx.x;
    int m0 = blockIdx.y * 64;
    int kbase = sk * (K / SPLITK);
    f32x4 acc[2][5];
    #pragma unroll
    for (int m = 0; m < 2; ++m)
        #pragma unroll
        for (int n = 0; n < 5; ++n) acc[m][n] = (f32x4){0.f, 0.f, 0.f, 0.f};
    int l15 = lane & 15, kq = lane >> 4;

    for (int ks = 0; ks < K / SPLITK; ks += 32) {
        int k0 = kbase + ks;
        {
            int s = tid;
            int row = s >> 2, kg = s & 3;
            int kgl = kg ^ ((row >> 1) & 3);
            __builtin_amdgcn_global_load_lds(
                (const __attribute__((address_space(1))) void*)(A + (long)(m0 + row) * K + k0 + kgl * 8),
                (__attribute__((address_space(3))) void*)(Al + s * 8), 16, 0, 0);
        }
        #pragma unroll
        for (int i = 0; i < 3; ++i) {
            int s = i * 256 + tid;
            if (s < 640) {
                int row = s >> 2, kg = s & 3;
                int kgl = kg ^ ((row >> 1) & 3);
                __builtin_amdgcn_global_load_lds(
                    (const __attribute__((address_space(1))) void*)(Bt + (long)row * K + k0 + kgl * 8),
                    (__attribute__((address_space(3))) void*)(Bl + s * 8), 16, 0, 0);
            }
        }
        __syncthreads();
        short8 af[2], bf[5];
        #pragma unroll
        for (int m = 0; m < 2; ++m) {
            int row = wr * 32 + m * 16 + l15;
            af[m] = *(const short8*)&Al[row * 32 + (kq ^ ((row >> 1) & 3)) * 8];
        }
        #pragma unroll
        for (int n = 0; n < 5; ++n) {
            int row = wc * 80 + n * 16 + l15;
            bf[n] = *(const short8*)&Bl[row * 32 + (kq ^ ((row >> 1) & 3)) * 8];
        }
        #pragma unroll
        for (int m = 0; m < 2; ++m)
            #pragma unroll
            for (int n = 0; n < 5; ++n)
                acc[m][n] = __builtin_amdgcn_mfma_f32_16x16x32_bf16(af[m], bf[n], acc[m][n], 0, 0, 0);
        __syncthreads();
    }
    float* P = Ppart + (long)sk * M * XPJ_N;
    #pragma unroll
    for (int m = 0; m < 2; ++m) {
        #pragma unroll
        for (int n = 0; n < 5; ++n) {
            #pragma unroll
            for (int r = 0; r < 4; ++r) {
                int row = m0 + wr * 32 + m * 16 + kq * 4 + r;
                int col = wc * 80 + n * 16 + l15;
                P[(long)row * XPJ_N + col] = acc[m][n][r];
            }
        }
    }
}

// -------- reduce split-K partials → xpj f32 + dt_r bf16 --------
__global__ __launch_bounds__(256) void reduce_xpj_kernel(const float* __restrict__ Ppart,
                                                         float* __restrict__ xpj,
                                                         ushort* __restrict__ dtr)
{
    long i = (long)blockIdx.x * 256 + threadIdx.x;
    float s = 0.f;
    #pragma unroll
    for (int k = 0; k < SPLITK; ++k) s += Ppart[k * (long)NTOK * XPJ_N + i];
    xpj[i] = s;
    int col = (int)(i % XPJ_N);
    long row = i / XPJ_N;
    if (col < DT_RANK) dtr[row * DT_RANK + col] = f2bf_bits(s);
}

// ---------------- depthwise causal conv (width 4) + bias + SiLU; bf16 in/out ----------
__global__ __launch_bounds__(256) void conv_silu_kernel(const ushort* __restrict__ xzb,
                                                        const float* __restrict__ cw,
                                                        const float* __restrict__ cb,
                                                        ushort* __restrict__ xbb)
{
    long i = (long)blockIdx.x * 256 + threadIdx.x;  // over NTOK*D_INNER
    int d = (int)(i & (D_INNER - 1));
    long tok = i >> 11;
    int l = (int)(tok & (SEQLEN - 1));
    float w0 = cw[d * 4 + 0], w1 = cw[d * 4 + 1], w2 = cw[d * 4 + 2], w3 = cw[d * 4 + 3];
    float acc = cb[d];
    acc += bf2f(xzb[tok * NPROJ + d]) * w3;
    if (l >= 1) acc += bf2f(xzb[(tok - 1) * NPROJ + d]) * w2;
    if (l >= 2) acc += bf2f(xzb[(tok - 2) * NPROJ + d]) * w1;
    if (l >= 3) acc += bf2f(xzb[(tok - 3) * NPROJ + d]) * w0;
    float v = acc * sigmoidf_(acc);
    xbb[i] = f2bf_bits(v);
}

// ======================= chunked selective scan: 1 LANE PER CHANNEL ===================
// Lane owns all 16 states in registers. dl/x/z coalesced (64 consecutive channels/wave);
// B/C rows block-uniform. No cross-lane ops.
// Block: 256 threads = 256 channels of one (b, chunk). Grid: BATCH*NCHUNK*8 = 512.

__global__ __launch_bounds__(256) void scan_partial_kernel(const ushort* __restrict__ deltab,
                                                           const ushort* __restrict__ xbb,
                                                           const float* __restrict__ xpj,
                                                           const float* __restrict__ A_log,
                                                           float* __restrict__ Pout,
                                                           float* __restrict__ Hout)
{
    int blk = blockIdx.x;
    int db = blk & 7;
    int c  = (blk >> 3) & (NCHUNK - 1);
    int b  = blk >> (3 + LOG2_NCHUNK);
    int d  = db * 256 + threadIdx.x;
    float a[16], h[16];
    #pragma unroll
    for (int q = 0; q < 4; ++q) {
        float4 al = *(const float4*)&A_log[d * D_STATE + q * 4];
        a[q*4+0] = -__expf(al.x) * LOG2E;
        a[q*4+1] = -__expf(al.y) * LOG2E;
        a[q*4+2] = -__expf(al.z) * LOG2E;
        a[q*4+3] = -__expf(al.w) * LOG2E;
    }
    #pragma unroll
    for (int n = 0; n < 16; ++n) h[n] = 0.f;
    float cum = 0.f;
    long tok0 = (long)b * SEQLEN + c * CHUNK;
    const ushort* dp = deltab + tok0 * D_INNER + d;
    const ushort* xp = xbb + tok0 * D_INNER + d;
    const float* Bbase = xpj + tok0 * XPJ_N + DT_RANK;   // block-uniform
    for (int t = 0; t < CHUNK; ++t) {
        float dl = bf2f(dp[(long)t * D_INNER]);
        float x  = bf2f(xp[(long)t * D_INNER]);
        float ux = dl * x;
        cum += dl;
        const float* Bp = Bbase + (long)t * XPJ_N;
        #pragma unroll
        for (int q = 0; q < 4; ++q) {
            float4 Bv = *(const float4*)(Bp + q * 4);
            h[q*4+0] = exp2f(dl * a[q*4+0]) * h[q*4+0] + ux * Bv.x;
            h[q*4+1] = exp2f(dl * a[q*4+1]) * h[q*4+1] + ux * Bv.y;
            h[q*4+2] = exp2f(dl * a[q*4+2]) * h[q*4+2] + ux * Bv.z;
            h[q*4+3] = exp2f(dl * a[q*4+3]) * h[q*4+3] + ux * Bv.w;
        }
    }
    long chbase = ((long)(b * NCHUNK + c) * D_INNER + d) * D_STATE;
    #pragma unroll
    for (int q = 0; q < 4; ++q) {
        float4 pv = {exp2f(a[q*4+0] * cum), exp2f(a[q*4+1] * cum),
                     exp2f(a[q*4+2] * cum), exp2f(a[q*4+3] * cum)};
        *(float4*)&Pout[chbase + q * 4] = pv;
        float4 hv = {h[q*4+0], h[q*4+1], h[q*4+2], h[q*4+3]};
        *(float4*)&Hout[chbase + q * 4] = hv;
    }
}

__global__ __launch_bounds__(256) void scan_chunkscan_kernel(const float* __restrict__ P,
                                                             const float* __restrict__ H,
                                                             float* __restrict__ hinit)
{
    long i = (long)blockIdx.x * 256 + threadIdx.x;  // over BATCH*D_INNER*D_STATE
    int n = (int)(i & (D_STATE - 1));
    int d = (int)((i >> 4) & (D_INNER - 1));
    int b = (int)(i >> 15);
    float h = 0.f;
    for (int c = 0; c < NCHUNK; ++c) {
        long o = ((((long)b * NCHUNK + c) * D_INNER + d) * D_STATE) + n;
        hinit[o] = h;
        h = P[o] * h + H[o];
    }
}

__global__ __launch_bounds__(256) void scan_final_kernel(const ushort* __restrict__ deltab,
                                                         const ushort* __restrict__ xbb,
                                                         const float* __restrict__ xpj,
                                                         const ushort* __restrict__ xzb,
                                                         const float* __restrict__ A_log,
                                                         const float* __restrict__ Dp,
                                                         const float* __restrict__ hinit,
                                                         ushort* __restrict__ yb)
{
    int blk = blockIdx.x;
    int db = blk & 7;
    int c  = (blk >> 3) & (NCHUNK - 1);
    int b  = blk >> (3 + LOG2_NCHUNK);
    int d  = db * 256 + threadIdx.x;
    float a[16], h[16];
    #pragma unroll
    for (int q = 0; q < 4; ++q) {
        float4 al = *(const float4*)&A_log[d * D_STATE + q * 4];
        a[q*4+0] = -__expf(al.x) * LOG2E;
        a[q*4+1] = -__expf(al.y) * LOG2E;
        a[q*4+2] = -__expf(al.z) * LOG2E;
        a[q*4+3] = -__expf(al.w) * LOG2E;
    }
    long chbase = ((long)(b * NCHUNK + c) * D_INNER + d) * D_STATE;
    #pragma unroll
    for (int q = 0; q < 4; ++q) {
        float4 hv = *(const float4*)&hinit[chbase + q * 4];
        h[q*4+0] = hv.x; h[q*4+1] = hv.y; h[q*4+2] = hv.z; h[q*4+3] = hv.w;
    }
    float dpar = Dp[d];
    long tok0 = (long)b * SEQLEN + c * CHUNK;
    const ushort* dp = deltab + tok0 * D_INNER + d;
    const ushort* xp = xbb + tok0 * D_INNER + d;
    const ushort* zp = xzb + tok0 * NPROJ + D_INNER + d;
    ushort* yp = yb + tok0 * D_INNER + d;
    const float* Bbase = xpj + tok0 * XPJ_N + DT_RANK;   // block-uniform
    for (int t = 0; t < CHUNK; ++t) {
        float dl = bf2f(dp[(long)t * D_INNER]);
        float x  = bf2f(xp[(long)t * D_INNER]);
        float z  = bf2f(zp[(long)t * NPROJ]);
        float ux = dl * x;
        const float* Bp = Bbase + (long)t * XPJ_N;
        float y = 0.f;
        #pragma unroll
        for (int q = 0; q < 4; ++q) {
            float4 Bv = *(const float4*)(Bp + q * 4);
            float4 Cv = *(const float4*)(Bp + D_STATE + q * 4);
            h[q*4+0] = exp2f(dl * a[q*4+0]) * h[q*4+0] + ux * Bv.x;
            h[q*4+1] = exp2f(dl * a[q*4+1]) * h[q*4+1] + ux * Bv.y;
            h[q*4+2] = exp2f(dl * a[q*4+2]) * h[q*4+2] + ux * Bv.z;
            h[q*4+3] = exp2f(dl * a[q*4+3]) * h[q*4+3] + ux * Bv.w;
            y += h[q*4+0] * Cv.x + h[q*4+1] * Cv.y + h[q*4+2] * Cv.z + h[q*4+3] * Cv.w;
        }
        y += x * dpar;
        yp[(long)t * D_INNER] = f2bf_bits(y * (z * sigmoidf_(z)));
    }
}

extern "C" void kernel_launch(void* const* d_in, const int* in_sizes, int n_in,
                              void* d_out, int out_size, void* d_ws, size_t ws_size,
                              hipStream_t stream) {
    const float* x         = (const float*)d_in[0];
    const float* ln_gamma  = (const float*)d_in[1];
    const float* ln_beta   = (const float*)d_in[2];
    const float* in_proj_w = (const float*)d_in[3];
    const float* conv_w    = (const float*)d_in[4];
    const float* conv_b    = (const float*)d_in[5];
    const float* x_proj_w  = (const float*)d_in[6];
    const float* dt_proj_w = (const float*)d_in[7];
    const float* dt_proj_b = (const float*)d_in[8];
    const float* A_log     = (const float*)d_in[9];
    const float* D_param   = (const float*)d_in[10];
    const float* out_proj_w= (const float*)d_in[11];
    float* out = (float*)d_out;

    // Clean disjoint arena (d_ws ≈ 268 MB; used ≈ 150 MB).
    float* p = (float*)d_ws;
    ushort* hb      = (ushort*)p; p += 1048576;   // [2048][1024] bf16
    ushort* W2T     = (ushort*)p; p += 2097152;   // [4096][1024] bf16
    ushort* W7T     = (ushort*)p; p += 1048576;   // [1024][2048] bf16
    ushort* XPT     = (ushort*)p; p += 163840;    // [160][2048] bf16
    ushort* DTT     = (ushort*)p; p += 131072;    // [2048][128] bf16
    ushort* xz_bf16 = (ushort*)p; p += 4194304;   // [2048 tok][4096] bf16
    ushort* xb_bf16 = (ushort*)p; p += 2097152;   // [tok][2048] bf16
    float*  xpj     = p;          p += 327680;    // [tok][160] f32
    ushort* dtr     = (ushort*)p; p += 131072;    // [tok][128] bf16
    ushort* delta_bf16 = (ushort*)p; p += 2097152;// [tok][2048] bf16
    float*  Ppart   = p;          p += 2621440;   // gemm4 partials [8][2048][160]
    float*  Pbuf    = p;          p += 2097152;   // scan P
    float*  Hbuf    = p;          p += 2097152;   // scan H
    float*  hinit   = p;          p += 2097152;
    ushort* y_bf16  = (ushort*)p; p += 2097152;   // [tok][2048] bf16
    float*  PpartO  = p;          p += 8388608;   // out_proj partials [4][2048][1024]

    // 0. weight transposes
    transpose_bf16_kernel<<<dim3(NPROJ / 64, D_MODEL / 64), 256, 0, stream>>>(
        in_proj_w, W2T, D_MODEL, NPROJ);
    transpose_bf16_kernel<<<dim3(D_MODEL / 64, D_INNER / 64), 256, 0, stream>>>(
        out_proj_w, W7T, D_INNER, D_MODEL);
    transpose_bf16_kernel<<<dim3((XPJ_N + 63) / 64, D_INNER / 64), 256, 0, stream>>>(
        x_proj_w, XPT, D_INNER, XPJ_N);
    transpose_bf16_kernel<<<dim3(D_INNER / 64, DT_RANK / 64), 256, 0, stream>>>(
        dt_proj_w, DTT, DT_RANK, D_INNER);

    // 1. LayerNorm → bf16
    ln_kernel<<<NTOK, 256, 0, stream>>>(x, ln_gamma, ln_beta, hb);

    // 2. xz = h @ in_proj_w (MFMA, bf16 out) [2048,1024]x[1024,4096]
    gemm_mfma_kernel<0, 1><<<dim3(NPROJ / 128, NTOK / 128), 256, 0, stream>>>(
        hb, W2T, nullptr, nullptr, xz_bf16, NTOK, NPROJ, D_MODEL, D_MODEL, D_MODEL);

    // 3. conv4 + bias + SiLU (bf16 in/out)
    conv_silu_kernel<<<(NTOK * D_INNER) / 256, 256, 0, stream>>>(
        xz_bf16, conv_w, conv_b, xb_bf16);

    // 4. xpj partials (split-K MFMA) then reduce → xpj f32 + dtr bf16
    gemm4_mfma_kernel<<<dim3(SPLITK, NTOK / 64), 256, 0, stream>>>(
        xb_bf16, XPT, Ppart, NTOK, D_INNER);
    reduce_xpj_kernel<<<(NTOK * XPJ_N) / 256, 256, 0, stream>>>(Ppart, xpj, dtr);

    // 5. delta = softplus(dt_r @ dt_proj_w + b) (MFMA 128x64, bf16 out)
    gemm_mfma64_kernel<1, 1><<<dim3(D_INNER / 64, NTOK / 128), 256, 0, stream>>>(
        dtr, DTT, dt_proj_b, nullptr, delta_bf16, NTOK, D_INNER, DT_RANK);

    // 6. chunked selective scan (1 lane/channel, 16 states in regs)
    scan_partial_kernel<<<BATCH * NCHUNK * 8, 256, 0, stream>>>(
        delta_bf16, xb_bf16, xpj, A_log, Pbuf, Hbuf);
    scan_chunkscan_kernel<<<(BATCH * D_INNER * D_STATE) / 256, 256, 0, stream>>>(
        Pbuf, Hbuf, hinit);
    scan_final_kernel<<<BATCH * NCHUNK * 8, 256, 0, stream>>>(
        delta_bf16, xb_bf16, xpj, xz_bf16, A_log, D_param, hinit, y_bf16);

    // 7. out_proj split-K=4: partials then fused reduce+residual
    gemm_mfma_kernel<0, 0><<<dim3(D_MODEL / 128, NTOK / 128, OP_SPLITK), 256, 0, stream>>>(
        y_bf16, W7T, nullptr, PpartO, nullptr, NTOK, D_MODEL, D_INNER / OP_SPLITK,
        D_INNER, D_INNER);
    reduce_out_kernel<<<(NTOK * D_MODEL / 4) / 256, 256, 0, stream>>>(PpartO, x, out);
}

// Round 14
// 193.217 us; speedup vs baseline: 1.0795x; 1.0795x over previous
//
#include <hip/hip_runtime.h>
#include <hip/hip_bf16.h>

#define D_MODEL 1024
#define D_INNER 2048
#define NPROJ   4096   /* 2*D_INNER */
#define D_STATE 16
#define DT_RANK 128
#define XPJ_N   160    /* DT_RANK + 2*D_STATE */
#define SEQLEN  1024
#define BATCH   2
#define NTOK    2048   /* BATCH*SEQLEN */
#define CHUNK   16
#define NCHUNK  (SEQLEN / CHUNK)   /* 64 */
#define LOG2_NCHUNK 6
#define SPLITK  8      /* gemm4 split */
#define OP_SPLITK 4    /* out_proj split */

typedef short short8 __attribute__((ext_vector_type(8)));
typedef float f32x4 __attribute__((ext_vector_type(4)));

__device__ __forceinline__ float sigmoidf_(float x) { return 1.f / (1.f + __expf(-x)); }
__device__ __forceinline__ ushort f2bf_bits(float f) {
    __hip_bfloat16 h = __float2bfloat16(f);
    return *(ushort*)&h;
}
__device__ __forceinline__ float bf2f(ushort u) {
    union { unsigned int i; float f; } v;
    v.i = ((unsigned int)u) << 16;
    return v.f;
}
#define LOG2E 1.44269504088896f

// ---------------- LayerNorm → bf16 output ----------------
__global__ __launch_bounds__(256) void ln_kernel(const float* __restrict__ x,
                                                 const float* __restrict__ g,
                                                 const float* __restrict__ be,
                                                 ushort* __restrict__ hb)
{
    int row = blockIdx.x;
    const float4* xr = (const float4*)(x + (long)row * D_MODEL);
    float4 v = xr[threadIdx.x];
    float s1 = v.x + v.y + v.z + v.w;
    float s2 = v.x*v.x + v.y*v.y + v.z*v.z + v.w*v.w;
    for (int off = 32; off >= 1; off >>= 1) {
        s1 += __shfl_down(s1, off);
        s2 += __shfl_down(s2, off);
    }
    __shared__ float red[8];
    int wid = threadIdx.x >> 6;
    if ((threadIdx.x & 63) == 0) { red[wid] = s1; red[4 + wid] = s2; }
    __syncthreads();
    float mu  = (red[0] + red[1] + red[2] + red[3]) * (1.f / D_MODEL);
    float ex2 = (red[4] + red[5] + red[6] + red[7]) * (1.f / D_MODEL);
    float inv = rsqrtf(ex2 - mu * mu + 1e-5f);
    float4 g4 = ((const float4*)g)[threadIdx.x];
    float4 b4 = ((const float4*)be)[threadIdx.x];
    ushort4 o;
    o.x = f2bf_bits((v.x - mu) * inv * g4.x + b4.x);
    o.y = f2bf_bits((v.y - mu) * inv * g4.y + b4.y);
    o.z = f2bf_bits((v.z - mu) * inv * g4.z + b4.z);
    o.w = f2bf_bits((v.w - mu) * inv * g4.w + b4.w);
    *(ushort4*)(hb + (long)row * D_MODEL + threadIdx.x * 4) = o;
}

// ---------------- batched f32 [R][C] → bf16 [C][R] transpose (4 weights, 1 dispatch) --
__device__ __forceinline__ void transpose_tile(const float* __restrict__ in,
                                               ushort* __restrict__ out,
                                               int R, int C, int cx, int ry)
{
    __shared__ float tile[64][65];
    int c0 = cx * 64, r0 = ry * 64;
    #pragma unroll
    for (int i = 0; i < 16; ++i) {
        int idx = threadIdx.x + i * 256;
        int r = idx >> 6, c = idx & 63;
        tile[r][c] = (r0 + r < R && c0 + c < C) ? in[(long)(r0 + r) * C + (c0 + c)] : 0.f;
    }
    __syncthreads();
    #pragma unroll
    for (int i = 0; i < 16; ++i) {
        int idx = threadIdx.x + i * 256;
        int cc = idx >> 6, rr = idx & 63;
        if (c0 + cc < C && r0 + rr < R)
            out[(long)(c0 + cc) * R + (r0 + rr)] = f2bf_bits(tile[rr][cc]);
    }
}

__global__ __launch_bounds__(256) void transpose_all_kernel(const float* __restrict__ w2,
                                                            ushort* __restrict__ W2T,
                                                            const float* __restrict__ w7,
                                                            ushort* __restrict__ W7T,
                                                            const float* __restrict__ xp,
                                                            ushort* __restrict__ XPT,
                                                            const float* __restrict__ dt,
                                                            ushort* __restrict__ DTT)
{
    int idx = blockIdx.x;
    if (idx < 1024) {                     // in_proj: R=1024, C=4096, grid (64,16)
        transpose_tile(w2, W2T, D_MODEL, NPROJ, idx & 63, idx >> 6);
    } else if (idx < 1536) {              // out_proj: R=2048, C=1024, grid (16,32)
        int rel = idx - 1024;
        transpose_tile(w7, W7T, D_INNER, D_MODEL, rel & 15, rel >> 4);
    } else if (idx < 1632) {              // x_proj: R=2048, C=160, grid (3,32)
        int rel = idx - 1536;
        transpose_tile(xp, XPT, D_INNER, XPJ_N, rel % 3, rel / 3);
    } else {                              // dt_proj: R=128, C=2048, grid (32,2)
        int rel = idx - 1632;
        transpose_tile(dt, DTT, DT_RANK, D_INNER, rel & 31, rel >> 5);
    }
}

// ---------------- bf16 MFMA GEMM 128x128: C = A[M,K(lda)] * Bt[N,K(ldb)]^T -----------
// XCD-aware bijective swizzle of (bx,by) — requires gridDim.x*gridDim.y % 8 == 0.
template <int EPI, int OBF>
__global__ __launch_bounds__(256) void gemm_mfma_kernel(const ushort* __restrict__ A,
                                                        const ushort* __restrict__ Bt,
                                                        const float* __restrict__ bias,
                                                        float* __restrict__ Cf,
                                                        ushort* __restrict__ Cb,
                                                        int M, int N, int K, int lda, int ldb)
{
    long zoff = (long)blockIdx.z;
    A  += zoff * K;
    Bt += zoff * K;
    if (OBF == 0) Cf += zoff * (long)M * N;
    int lin = blockIdx.y * gridDim.x + blockIdx.x;
    int cpx = (gridDim.x * gridDim.y) >> 3;
    lin = (lin & 7) * cpx + (lin >> 3);
    int bx = lin % gridDim.x, by = lin / gridDim.x;
    __shared__ __align__(16) ushort Al[128 * 32];
    __shared__ __align__(16) ushort Bl[128 * 32];
    int tid = threadIdx.x;
    int lane = tid & 63;
    int w = tid >> 6, wr = w >> 1, wc = w & 1;
    int m0 = by * 128, n0 = bx * 128;
    f32x4 acc[4][4];
    #pragma unroll
    for (int m = 0; m < 4; ++m)
        #pragma unroll
        for (int n = 0; n < 4; ++n) acc[m][n] = (f32x4){0.f, 0.f, 0.f, 0.f};
    int l15 = lane & 15, kq = lane >> 4;

    for (int k0 = 0; k0 < K; k0 += 32) {
        #pragma unroll
        for (int i = 0; i < 2; ++i) {
            int s = i * 256 + tid;
            int row = s >> 2, kg = s & 3;
            int kgl = kg ^ ((row >> 1) & 3);
            __builtin_amdgcn_global_load_lds(
                (const __attribute__((address_space(1))) void*)(A + (long)(m0 + row) * lda + k0 + kgl * 8),
                (__attribute__((address_space(3))) void*)(Al + s * 8), 16, 0, 0);
            __builtin_amdgcn_global_load_lds(
                (const __attribute__((address_space(1))) void*)(Bt + (long)(n0 + row) * ldb + k0 + kgl * 8),
                (__attribute__((address_space(3))) void*)(Bl + s * 8), 16, 0, 0);
        }
        __syncthreads();
        short8 af[4], bf[4];
        #pragma unroll
        for (int m = 0; m < 4; ++m) {
            int row = wr * 64 + m * 16 + l15;
            af[m] = *(const short8*)&Al[row * 32 + (kq ^ ((row >> 1) & 3)) * 8];
        }
        #pragma unroll
        for (int n = 0; n < 4; ++n) {
            int row = wc * 64 + n * 16 + l15;
            bf[n] = *(const short8*)&Bl[row * 32 + (kq ^ ((row >> 1) & 3)) * 8];
        }
        #pragma unroll
        for (int m = 0; m < 4; ++m)
            #pragma unroll
            for (int n = 0; n < 4; ++n)
                acc[m][n] = __builtin_amdgcn_mfma_f32_16x16x32_bf16(af[m], bf[n], acc[m][n], 0, 0, 0);
        __syncthreads();
    }
    #pragma unroll
    for (int m = 0; m < 4; ++m) {
        #pragma unroll
        for (int n = 0; n < 4; ++n) {
            #pragma unroll
            for (int r = 0; r < 4; ++r) {
                int row = m0 + wr * 64 + m * 16 + kq * 4 + r;
                int col = n0 + wc * 64 + n * 16 + l15;
                float v = acc[m][n][r];
                if (EPI == 1) {
                    v += bias[col];
                    v = (v > 20.f) ? v : log1pf(__expf(v));
                }
                if (OBF) Cb[(long)row * N + col] = f2bf_bits(v);
                else     Cf[(long)row * N + col] = v;
            }
        }
    }
}

// ---------------- bf16 MFMA GEMM 128x64 (XCD-swizzled) ----------------
template <int EPI, int OBF>
__global__ __launch_bounds__(256) void gemm_mfma64_kernel(const ushort* __restrict__ A,
                                                          const ushort* __restrict__ Bt,
                                                          const float* __restrict__ bias,
                                                          float* __restrict__ Cf,
                                                          ushort* __restrict__ Cb,
                                                          int M, int N, int K)
{
    int lin = blockIdx.y * gridDim.x + blockIdx.x;
    int cpx = (gridDim.x * gridDim.y) >> 3;
    lin = (lin & 7) * cpx + (lin >> 3);
    int bx = lin % gridDim.x, by = lin / gridDim.x;
    __shared__ __align__(16) ushort Al[128 * 32];
    __shared__ __align__(16) ushort Bl[64 * 32];
    int tid = threadIdx.x;
    int lane = tid & 63;
    int w = tid >> 6, wr = w >> 1, wc = w & 1;
    int m0 = by * 128, n0 = bx * 64;
    f32x4 acc[4][2];
    #pragma unroll
    for (int m = 0; m < 4; ++m)
        #pragma unroll
        for (int n = 0; n < 2; ++n) acc[m][n] = (f32x4){0.f, 0.f, 0.f, 0.f};
    int l15 = lane & 15, kq = lane >> 4;

    for (int k0 = 0; k0 < K; k0 += 32) {
        #pragma unroll
        for (int i = 0; i < 2; ++i) {
            int s = i * 256 + tid;
            int row = s >> 2, kg = s & 3;
            int kgl = kg ^ ((row >> 1) & 3);
            __builtin_amdgcn_global_load_lds(
                (const __attribute__((address_space(1))) void*)(A + (long)(m0 + row) * K + k0 + kgl * 8),
                (__attribute__((address_space(3))) void*)(Al + s * 8), 16, 0, 0);
        }
        {
            int s = tid;
            int row = s >> 2, kg = s & 3;
            int kgl = kg ^ ((row >> 1) & 3);
            __builtin_amdgcn_global_load_lds(
                (const __attribute__((address_space(1))) void*)(Bt + (long)(n0 + row) * K + k0 + kgl * 8),
                (__attribute__((address_space(3))) void*)(Bl + s * 8), 16, 0, 0);
        }
        __syncthreads();
        short8 af[4], bf[2];
        #pragma unroll
        for (int m = 0; m < 4; ++m) {
            int row = wr * 64 + m * 16 + l15;
            af[m] = *(const short8*)&Al[row * 32 + (kq ^ ((row >> 1) & 3)) * 8];
        }
        #pragma unroll
        for (int n = 0; n < 2; ++n) {
            int row = wc * 32 + n * 16 + l15;
            bf[n] = *(const short8*)&Bl[row * 32 + (kq ^ ((row >> 1) & 3)) * 8];
        }
        #pragma unroll
        for (int m = 0; m < 4; ++m)
            #pragma unroll
            for (int n = 0; n < 2; ++n)
                acc[m][n] = __builtin_amdgcn_mfma_f32_16x16x32_bf16(af[m], bf[n], acc[m][n], 0, 0, 0);
        __syncthreads();
    }
    #pragma unroll
    for (int m = 0; m < 4; ++m) {
        #pragma unroll
        for (int n = 0; n < 2; ++n) {
            #pragma unroll
            for (int r = 0; r < 4; ++r) {
                int row = m0 + wr * 64 + m * 16 + kq * 4 + r;
                int col = n0 + wc * 32 + n * 16 + l15;
                float v = acc[m][n][r];
                if (EPI == 1) {
                    v += bias[col];
                    v = (v > 20.f) ? v : log1pf(__expf(v));
                }
                if (OBF) Cb[(long)row * N + col] = f2bf_bits(v);
                else     Cf[(long)row * N + col] = v;
            }
        }
    }
}

// -------- out_proj split-K reduce: out = sum_k Ppart[k] + resid --------
__global__ __launch_bounds__(256) void reduce_out_kernel(const float* __restrict__ Ppart,
                                                         const float* __restrict__ resid,
                                                         float* __restrict__ out)
{
    long i = (long)blockIdx.x * 256 + threadIdx.x;
    const long STRIDE = (long)NTOK * D_MODEL / 4;
    float4 s = ((const float4*)Ppart)[i];
    #pragma unroll
    for (int k = 1; k < OP_SPLITK; ++k) {
        float4 p = ((const float4*)Ppart)[k * STRIDE + i];
        s.x += p.x; s.y += p.y; s.z += p.z; s.w += p.w;
    }
    float4 r = ((const float4*)resid)[i];
    s.x += r.x; s.y += r.y; s.z += r.z; s.w += r.w;
    ((float4*)out)[i] = s;
}

// -------- split-K bf16 MFMA GEMM for xpj --------
__global__ __launch_bounds__(256) void gemm4_mfma_kernel(const ushort* __restrict__ A,
                                                         const ushort* __restrict__ Bt,
                                                         float* __restrict__ Ppart,
                                                         int M, int K)
{
    __shared__ __align__(16) ushort Al[64 * 32];
    __shared__ __align__(16) ushort Bl[160 * 32];
    int tid = threadIdx.x;
    int lane = tid & 63;
    int w = tid >> 6, wr = w >> 1, wc = w & 1;
    int sk = blockIdx.x;
    int m0 = blockIdx.y * 64;
    int kbase = sk * (K / SPLITK);
    f32x4 acc[2][5];
    #pragma unroll
    for (int m = 0; m < 2; ++m)
        #pragma unroll
        for (int n = 0; n < 5; ++n) acc[m][n] = (f32x4){0.f, 0.f, 0.f, 0.f};
    int l15 = lane & 15, kq = lane >> 4;

    for (int ks = 0; ks < K / SPLITK; ks += 32) {
        int k0 = kbase + ks;
        {
            int s = tid;
            int row = s >> 2, kg = s & 3;
            int kgl = kg ^ ((row >> 1) & 3);
            __builtin_amdgcn_global_load_lds(
                (const __attribute__((address_space(1))) void*)(A + (long)(m0 + row) * K + k0 + kgl * 8),
                (__attribute__((address_space(3))) void*)(Al + s * 8), 16, 0, 0);
        }
        #pragma unroll
        for (int i = 0; i < 3; ++i) {
            int s = i * 256 + tid;
            if (s < 640) {
                int row = s >> 2, kg = s & 3;
                int kgl = kg ^ ((row >> 1) & 3);
                __builtin_amdgcn_global_load_lds(
                    (const __attribute__((address_space(1))) void*)(Bt + (long)row * K + k0 + kgl * 8),
                    (__attribute__((address_space(3))) void*)(Bl + s * 8), 16, 0, 0);
            }
        }
        __syncthreads();
        short8 af[2], bf[5];
        #pragma unroll
        for (int m = 0; m < 2; ++m) {
            int row = wr * 32 + m * 16 + l15;
            af[m] = *(const short8*)&Al[row * 32 + (kq ^ ((row >> 1) & 3)) * 8];
        }
        #pragma unroll
        for (int n = 0; n < 5; ++n) {
            int row = wc * 80 + n * 16 + l15;
            bf[n] = *(const short8*)&Bl[row * 32 + (kq ^ ((row >> 1) & 3)) * 8];
        }
        #pragma unroll
        for (int m = 0; m < 2; ++m)
            #pragma unroll
            for (int n = 0; n < 5; ++n)
                acc[m][n] = __builtin_amdgcn_mfma_f32_16x16x32_bf16(af[m], bf[n], acc[m][n], 0, 0, 0);
        __syncthreads();
    }
    float* P = Ppart + (long)sk * M * XPJ_N;
    #pragma unroll
    for (int m = 0; m < 2; ++m) {
        #pragma unroll
        for (int n = 0; n < 5; ++n) {
            #pragma unroll
            for (int r = 0; r < 4; ++r) {
                int row = m0 + wr * 32 + m * 16 + kq * 4 + r;
                int col = wc * 80 + n * 16 + l15;
                P[(long)row * XPJ_N + col] = acc[m][n][r];
            }
        }
    }
}

// -------- reduce split-K partials → xpj f32 + dt_r bf16 --------
__global__ __launch_bounds__(256) void reduce_xpj_kernel(const float* __restrict__ Ppart,
                                                         float* __restrict__ xpj,
                                                         ushort* __restrict__ dtr)
{
    long i = (long)blockIdx.x * 256 + threadIdx.x;
    float s = 0.f;
    #pragma unroll
    for (int k = 0; k < SPLITK; ++k) s += Ppart[k * (long)NTOK * XPJ_N + i];
    xpj[i] = s;
    int col = (int)(i % XPJ_N);
    long row = i / XPJ_N;
    if (col < DT_RANK) dtr[row * DT_RANK + col] = f2bf_bits(s);
}

// ---------------- depthwise causal conv (width 4) + bias + SiLU; bf16 in/out ----------
__global__ __launch_bounds__(256) void conv_silu_kernel(const ushort* __restrict__ xzb,
                                                        const float* __restrict__ cw,
                                                        const float* __restrict__ cb,
                                                        ushort* __restrict__ xbb)
{
    long i = (long)blockIdx.x * 256 + threadIdx.x;  // over NTOK*D_INNER
    int d = (int)(i & (D_INNER - 1));
    long tok = i >> 11;
    int l = (int)(tok & (SEQLEN - 1));
    float w0 = cw[d * 4 + 0], w1 = cw[d * 4 + 1], w2 = cw[d * 4 + 2], w3 = cw[d * 4 + 3];
    float acc = cb[d];
    acc += bf2f(xzb[tok * NPROJ + d]) * w3;
    if (l >= 1) acc += bf2f(xzb[(tok - 1) * NPROJ + d]) * w2;
    if (l >= 2) acc += bf2f(xzb[(tok - 2) * NPROJ + d]) * w1;
    if (l >= 3) acc += bf2f(xzb[(tok - 3) * NPROJ + d]) * w0;
    float v = acc * sigmoidf_(acc);
    xbb[i] = f2bf_bits(v);
}

// ======================= chunked selective scan: 1 lane/channel, CHUNK=16 =============
// B/C staged in LDS once per block; per-token chain reads LDS broadcast.
// Block: 256 threads = 256 channels of one (b, chunk). Grid: BATCH*NCHUNK*8 = 1024.

__global__ __launch_bounds__(256) void scan_partial_kernel(const ushort* __restrict__ deltab,
                                                           const ushort* __restrict__ xbb,
                                                           const float* __restrict__ xpj,
                                                           const float* __restrict__ A_log,
                                                           float* __restrict__ Pout,
                                                           float* __restrict__ Hout)
{
    __shared__ float bc[CHUNK][32];
    int blk = blockIdx.x;
    int db = blk & 7;
    int c  = (blk >> 3) & (NCHUNK - 1);
    int b  = blk >> (3 + LOG2_NCHUNK);
    int d  = db * 256 + threadIdx.x;
    long tok0 = (long)b * SEQLEN + c * CHUNK;
    // cooperative stage of B,C rows (CHUNK x 32 f32)
    for (int i = threadIdx.x; i < CHUNK * 32; i += 256) {
        int t = i >> 5, cc = i & 31;
        bc[t][cc] = xpj[(tok0 + t) * XPJ_N + DT_RANK + cc];
    }
    float a[16], h[16];
    #pragma unroll
    for (int q = 0; q < 4; ++q) {
        float4 al = *(const float4*)&A_log[d * D_STATE + q * 4];
        a[q*4+0] = -__expf(al.x) * LOG2E;
        a[q*4+1] = -__expf(al.y) * LOG2E;
        a[q*4+2] = -__expf(al.z) * LOG2E;
        a[q*4+3] = -__expf(al.w) * LOG2E;
    }
    #pragma unroll
    for (int n = 0; n < 16; ++n) h[n] = 0.f;
    float cum = 0.f;
    const ushort* dp = deltab + tok0 * D_INNER + d;
    const ushort* xp = xbb + tok0 * D_INNER + d;
    __syncthreads();
    for (int t = 0; t < CHUNK; ++t) {
        float dl = bf2f(dp[(long)t * D_INNER]);
        float x  = bf2f(xp[(long)t * D_INNER]);
        float ux = dl * x;
        cum += dl;
        #pragma unroll
        for (int q = 0; q < 4; ++q) {
            float4 Bv = *(const float4*)&bc[t][q * 4];
            h[q*4+0] = exp2f(dl * a[q*4+0]) * h[q*4+0] + ux * Bv.x;
            h[q*4+1] = exp2f(dl * a[q*4+1]) * h[q*4+1] + ux * Bv.y;
            h[q*4+2] = exp2f(dl * a[q*4+2]) * h[q*4+2] + ux * Bv.z;
            h[q*4+3] = exp2f(dl * a[q*4+3]) * h[q*4+3] + ux * Bv.w;
        }
    }
    long chbase = ((long)(b * NCHUNK + c) * D_INNER + d) * D_STATE;
    #pragma unroll
    for (int q = 0; q < 4; ++q) {
        float4 pv = {exp2f(a[q*4+0] * cum), exp2f(a[q*4+1] * cum),
                     exp2f(a[q*4+2] * cum), exp2f(a[q*4+3] * cum)};
        *(float4*)&Pout[chbase + q * 4] = pv;
        float4 hv = {h[q*4+0], h[q*4+1], h[q*4+2], h[q*4+3]};
        *(float4*)&Hout[chbase + q * 4] = hv;
    }
}

__global__ __launch_bounds__(256) void scan_chunkscan_kernel(const float* __restrict__ P,
                                                             const float* __restrict__ H,
                                                             float* __restrict__ hinit)
{
    long i = (long)blockIdx.x * 256 + threadIdx.x;  // over BATCH*D_INNER*D_STATE
    int n = (int)(i & (D_STATE - 1));
    int d = (int)((i >> 4) & (D_INNER - 1));
    int b = (int)(i >> 15);
    float h = 0.f;
    for (int c = 0; c < NCHUNK; ++c) {
        long o = ((((long)b * NCHUNK + c) * D_INNER + d) * D_STATE) + n;
        hinit[o] = h;
        h = P[o] * h + H[o];
    }
}

__global__ __launch_bounds__(256) void scan_final_kernel(const ushort* __restrict__ deltab,
                                                         const ushort* __restrict__ xbb,
                                                         const float* __restrict__ xpj,
                                                         const ushort* __restrict__ xzb,
                                                         const float* __restrict__ A_log,
                                                         const float* __restrict__ Dp,
                                                         const float* __restrict__ hinit,
                                                         ushort* __restrict__ yb)
{
    __shared__ float bc[CHUNK][32];
    int blk = blockIdx.x;
    int db = blk & 7;
    int c  = (blk >> 3) & (NCHUNK - 1);
    int b  = blk >> (3 + LOG2_NCHUNK);
    int d  = db * 256 + threadIdx.x;
    long tok0 = (long)b * SEQLEN + c * CHUNK;
    for (int i = threadIdx.x; i < CHUNK * 32; i += 256) {
        int t = i >> 5, cc = i & 31;
        bc[t][cc] = xpj[(tok0 + t) * XPJ_N + DT_RANK + cc];
    }
    float a[16], h[16];
    #pragma unroll
    for (int q = 0; q < 4; ++q) {
        float4 al = *(const float4*)&A_log[d * D_STATE + q * 4];
        a[q*4+0] = -__expf(al.x) * LOG2E;
        a[q*4+1] = -__expf(al.y) * LOG2E;
        a[q*4+2] = -__expf(al.z) * LOG2E;
        a[q*4+3] = -__expf(al.w) * LOG2E;
    }
    long chbase = ((long)(b * NCHUNK + c) * D_INNER + d) * D_STATE;
    #pragma unroll
    for (int q = 0; q < 4; ++q) {
        float4 hv = *(const float4*)&hinit[chbase + q * 4];
        h[q*4+0] = hv.x; h[q*4+1] = hv.y; h[q*4+2] = hv.z; h[q*4+3] = hv.w;
    }
    float dpar = Dp[d];
    const ushort* dp = deltab + tok0 * D_INNER + d;
    const ushort* xp = xbb + tok0 * D_INNER + d;
    const ushort* zp = xzb + tok0 * NPROJ + D_INNER + d;
    ushort* yp = yb + tok0 * D_INNER + d;
    __syncthreads();
    for (int t = 0; t < CHUNK; ++t) {
        float dl = bf2f(dp[(long)t * D_INNER]);
        float x  = bf2f(xp[(long)t * D_INNER]);
        float z  = bf2f(zp[(long)t * NPROJ]);
        float ux = dl * x;
        float y = 0.f;
        #pragma unroll
        for (int q = 0; q < 4; ++q) {
            float4 Bv = *(const float4*)&bc[t][q * 4];
            float4 Cv = *(const float4*)&bc[t][16 + q * 4];
            h[q*4+0] = exp2f(dl * a[q*4+0]) * h[q*4+0] + ux * Bv.x;
            h[q*4+1] = exp2f(dl * a[q*4+1]) * h[q*4+1] + ux * Bv.y;
            h[q*4+2] = exp2f(dl * a[q*4+2]) * h[q*4+2] + ux * Bv.z;
            h[q*4+3] = exp2f(dl * a[q*4+3]) * h[q*4+3] + ux * Bv.w;
            y += h[q*4+0] * Cv.x + h[q*4+1] * Cv.y + h[q*4+2] * Cv.z + h[q*4+3] * Cv.w;
        }
        y += x * dpar;
        yp[(long)t * D_INNER] = f2bf_bits(y * (z * sigmoidf_(z)));
    }
}

extern "C" void kernel_launch(void* const* d_in, const int* in_sizes, int n_in,
                              void* d_out, int out_size, void* d_ws, size_t ws_size,
                              hipStream_t stream) {
    const float* x         = (const float*)d_in[0];
    const float* ln_gamma  = (const float*)d_in[1];
    const float* ln_beta   = (const float*)d_in[2];
    const float* in_proj_w = (const float*)d_in[3];
    const float* conv_w    = (const float*)d_in[4];
    const float* conv_b    = (const float*)d_in[5];
    const float* x_proj_w  = (const float*)d_in[6];
    const float* dt_proj_w = (const float*)d_in[7];
    const float* dt_proj_b = (const float*)d_in[8];
    const float* A_log     = (const float*)d_in[9];
    const float* D_param   = (const float*)d_in[10];
    const float* out_proj_w= (const float*)d_in[11];
    float* out = (float*)d_out;

    // Clean disjoint arena (d_ws ≈ 268 MB; used ≈ 156 MB).
    float* p = (float*)d_ws;
    ushort* hb      = (ushort*)p; p += 1048576;   // [2048][1024] bf16
    ushort* W2T     = (ushort*)p; p += 2097152;   // [4096][1024] bf16
    ushort* W7T     = (ushort*)p; p += 1048576;   // [1024][2048] bf16
    ushort* XPT     = (ushort*)p; p += 163840;    // [160][2048] bf16
    ushort* DTT     = (ushort*)p; p += 131072;    // [2048][128] bf16
    ushort* xz_bf16 = (ushort*)p; p += 4194304;   // [2048 tok][4096] bf16
    ushort* xb_bf16 = (ushort*)p; p += 2097152;   // [tok][2048] bf16
    float*  xpj     = p;          p += 327680;    // [tok][160] f32
    ushort* dtr     = (ushort*)p; p += 131072;    // [tok][128] bf16
    ushort* delta_bf16 = (ushort*)p; p += 2097152;// [tok][2048] bf16
    float*  Ppart   = p;          p += 2621440;   // gemm4 partials [8][2048][160]
    float*  Pbuf    = p;          p += 4194304;   // scan P  [B][64][2048][16]
    float*  Hbuf    = p;          p += 4194304;   // scan H
    float*  hinit   = p;          p += 4194304;
    ushort* y_bf16  = (ushort*)p; p += 2097152;   // [tok][2048] bf16 = 4,194,304 ushorts
    float*  PpartO  = p;          p += 8388608;   // out_proj partials [4][2048][1024]

    // 0. all four weight transposes, one dispatch
    transpose_all_kernel<<<1696, 256, 0, stream>>>(
        in_proj_w, W2T, out_proj_w, W7T, x_proj_w, XPT, dt_proj_w, DTT);

    // 1. LayerNorm → bf16
    ln_kernel<<<NTOK, 256, 0, stream>>>(x, ln_gamma, ln_beta, hb);

    // 2. xz = h @ in_proj_w (MFMA, bf16 out, XCD swizzle) [2048,1024]x[1024,4096]
    gemm_mfma_kernel<0, 1><<<dim3(NPROJ / 128, NTOK / 128), 256, 0, stream>>>(
        hb, W2T, nullptr, nullptr, xz_bf16, NTOK, NPROJ, D_MODEL, D_MODEL, D_MODEL);

    // 3. conv4 + bias + SiLU (bf16 in/out)
    conv_silu_kernel<<<(NTOK * D_INNER) / 256, 256, 0, stream>>>(
        xz_bf16, conv_w, conv_b, xb_bf16);

    // 4. xpj partials (split-K MFMA) then reduce → xpj f32 + dtr bf16
    gemm4_mfma_kernel<<<dim3(SPLITK, NTOK / 64), 256, 0, stream>>>(
        xb_bf16, XPT, Ppart, NTOK, D_INNER);
    reduce_xpj_kernel<<<(NTOK * XPJ_N) / 256, 256, 0, stream>>>(Ppart, xpj, dtr);

    // 5. delta = softplus(dt_r @ dt_proj_w + b) (MFMA 128x64, bf16 out, XCD swizzle)
    gemm_mfma64_kernel<1, 1><<<dim3(D_INNER / 64, NTOK / 128), 256, 0, stream>>>(
        dtr, DTT, dt_proj_b, nullptr, delta_bf16, NTOK, D_INNER, DT_RANK);

    // 6. chunked selective scan (1 lane/channel, CHUNK=16, LDS-staged B/C)
    scan_partial_kernel<<<BATCH * NCHUNK * 8, 256, 0, stream>>>(
        delta_bf16, xb_bf16, xpj, A_log, Pbuf, Hbuf);
    scan_chunkscan_kernel<<<(BATCH * D_INNER * D_STATE) / 256, 256, 0, stream>>>(
        Pbuf, Hbuf, hinit);
    scan_final_kernel<<<BATCH * NCHUNK * 8, 256, 0, stream>>>(
        delta_bf16, xb_bf16, xpj, xz_bf16, A_log, D_param, hinit, y_bf16);

    // 7. out_proj split-K=4: partials then fused reduce+residual (XCD swizzle per slice)
    gemm_mfma_kernel<0, 0><<<dim3(D_MODEL / 128, NTOK / 128, OP_SPLITK), 256, 0, stream>>>(
        y_bf16, W7T, nullptr, PpartO, nullptr, NTOK, D_MODEL, D_INNER / OP_SPLITK,
        D_INNER, D_INNER);
    reduce_out_kernel<<<(NTOK * D_MODEL / 4) / 256, 256, 0, stream>>>(PpartO, x, out);
}

// Round 15
// 188.605 us; speedup vs baseline: 1.1059x; 1.0245x over previous
//
#include <hip/hip_runtime.h>
#include <hip/hip_bf16.h>

#define D_MODEL 1024
#define D_INNER 2048
#define NPROJ   4096   /* 2*D_INNER */
#define D_STATE 16
#define DT_RANK 128
#define XPJ_N   160    /* DT_RANK + 2*D_STATE */
#define SEQLEN  1024
#define BATCH   2
#define NTOK    2048   /* BATCH*SEQLEN */
#define CHUNK   16
#define NCHUNK  (SEQLEN / CHUNK)   /* 64 */
#define LOG2_NCHUNK 6
#define SPLITK  8      /* gemm4 split */
#define OP_SPLITK 4    /* out_proj split */

typedef short short8 __attribute__((ext_vector_type(8)));
typedef float f32x4 __attribute__((ext_vector_type(4)));

__device__ __forceinline__ float sigmoidf_(float x) { return 1.f / (1.f + __expf(-x)); }
__device__ __forceinline__ ushort f2bf_bits(float f) {
    __hip_bfloat16 h = __float2bfloat16(f);
    return *(ushort*)&h;
}
__device__ __forceinline__ float bf2f(ushort u) {
    union { unsigned int i; float f; } v;
    v.i = ((unsigned int)u) << 16;
    return v.f;
}
#define LOG2E 1.44269504088896f

// ---------------- LayerNorm → bf16 output ----------------
__global__ __launch_bounds__(256) void ln_kernel(const float* __restrict__ x,
                                                 const float* __restrict__ g,
                                                 const float* __restrict__ be,
                                                 ushort* __restrict__ hb)
{
    int row = blockIdx.x;
    const float4* xr = (const float4*)(x + (long)row * D_MODEL);
    float4 v = xr[threadIdx.x];
    float s1 = v.x + v.y + v.z + v.w;
    float s2 = v.x*v.x + v.y*v.y + v.z*v.z + v.w*v.w;
    for (int off = 32; off >= 1; off >>= 1) {
        s1 += __shfl_down(s1, off);
        s2 += __shfl_down(s2, off);
    }
    __shared__ float red[8];
    int wid = threadIdx.x >> 6;
    if ((threadIdx.x & 63) == 0) { red[wid] = s1; red[4 + wid] = s2; }
    __syncthreads();
    float mu  = (red[0] + red[1] + red[2] + red[3]) * (1.f / D_MODEL);
    float ex2 = (red[4] + red[5] + red[6] + red[7]) * (1.f / D_MODEL);
    float inv = rsqrtf(ex2 - mu * mu + 1e-5f);
    float4 g4 = ((const float4*)g)[threadIdx.x];
    float4 b4 = ((const float4*)be)[threadIdx.x];
    ushort4 o;
    o.x = f2bf_bits((v.x - mu) * inv * g4.x + b4.x);
    o.y = f2bf_bits((v.y - mu) * inv * g4.y + b4.y);
    o.z = f2bf_bits((v.z - mu) * inv * g4.z + b4.z);
    o.w = f2bf_bits((v.w - mu) * inv * g4.w + b4.w);
    *(ushort4*)(hb + (long)row * D_MODEL + threadIdx.x * 4) = o;
}

// ---------------- batched f32 [R][C] → bf16 [C][R] transpose (4 weights, 1 dispatch) --
__device__ __forceinline__ void transpose_tile(const float* __restrict__ in,
                                               ushort* __restrict__ out,
                                               int R, int C, int cx, int ry)
{
    __shared__ float tile[64][65];
    int c0 = cx * 64, r0 = ry * 64;
    #pragma unroll
    for (int i = 0; i < 16; ++i) {
        int idx = threadIdx.x + i * 256;
        int r = idx >> 6, c = idx & 63;
        tile[r][c] = (r0 + r < R && c0 + c < C) ? in[(long)(r0 + r) * C + (c0 + c)] : 0.f;
    }
    __syncthreads();
    #pragma unroll
    for (int i = 0; i < 16; ++i) {
        int idx = threadIdx.x + i * 256;
        int cc = idx >> 6, rr = idx & 63;
        if (c0 + cc < C && r0 + rr < R)
            out[(long)(c0 + cc) * R + (r0 + rr)] = f2bf_bits(tile[rr][cc]);
    }
}

__global__ __launch_bounds__(256) void transpose_all_kernel(const float* __restrict__ w2,
                                                            ushort* __restrict__ W2T,
                                                            const float* __restrict__ w7,
                                                            ushort* __restrict__ W7T,
                                                            const float* __restrict__ xp,
                                                            ushort* __restrict__ XPT,
                                                            const float* __restrict__ dt,
                                                            ushort* __restrict__ DTT)
{
    int idx = blockIdx.x;
    if (idx < 1024) {                     // in_proj: R=1024, C=4096, grid (64,16)
        transpose_tile(w2, W2T, D_MODEL, NPROJ, idx & 63, idx >> 6);
    } else if (idx < 1536) {              // out_proj: R=2048, C=1024, grid (16,32)
        int rel = idx - 1024;
        transpose_tile(w7, W7T, D_INNER, D_MODEL, rel & 15, rel >> 4);
    } else if (idx < 1632) {              // x_proj: R=2048, C=160, grid (3,32)
        int rel = idx - 1536;
        transpose_tile(xp, XPT, D_INNER, XPJ_N, rel % 3, rel / 3);
    } else {                              // dt_proj: R=128, C=2048, grid (32,2)
        int rel = idx - 1632;
        transpose_tile(dt, DTT, DT_RANK, D_INNER, rel & 31, rel >> 5);
    }
}

// ---------------- bf16 MFMA GEMM 128x128, 2-phase double-buffered pipeline -----------
// C = A[M,K(lda)] * Bt[N,K(ldb)]^T. XCD-swizzled; blockIdx.z = split-K slice.
// Counted vmcnt(4) keeps next-tile global_load_lds in flight across the barrier (T3/T4).
template <int EPI, int OBF>
__global__ __launch_bounds__(256) void gemm_mfma_kernel(const ushort* __restrict__ A,
                                                        const ushort* __restrict__ Bt,
                                                        const float* __restrict__ bias,
                                                        float* __restrict__ Cf,
                                                        ushort* __restrict__ Cb,
                                                        int M, int N, int K, int lda, int ldb)
{
    long zoff = (long)blockIdx.z;
    A  += zoff * K;
    Bt += zoff * K;
    if (OBF == 0) Cf += zoff * (long)M * N;
    int lin = blockIdx.y * gridDim.x + blockIdx.x;
    int cpx = (gridDim.x * gridDim.y) >> 3;
    lin = (lin & 7) * cpx + (lin >> 3);
    int bx = lin % gridDim.x, by = lin / gridDim.x;
    __shared__ __align__(16) ushort Al[2][128 * 32];
    __shared__ __align__(16) ushort Bl[2][128 * 32];
    int tid = threadIdx.x;
    int lane = tid & 63;
    int w = tid >> 6, wr = w >> 1, wc = w & 1;
    int m0 = by * 128, n0 = bx * 128;
    f32x4 acc[4][4];
    #pragma unroll
    for (int m = 0; m < 4; ++m)
        #pragma unroll
        for (int n = 0; n < 4; ++n) acc[m][n] = (f32x4){0.f, 0.f, 0.f, 0.f};
    int l15 = lane & 15, kq = lane >> 4;

    auto stage = [&](int buf, int k0) {
        #pragma unroll
        for (int i = 0; i < 2; ++i) {
            int s = i * 256 + tid;
            int row = s >> 2, kg = s & 3;
            int kgl = kg ^ ((row >> 1) & 3);
            __builtin_amdgcn_global_load_lds(
                (const __attribute__((address_space(1))) void*)(A + (long)(m0 + row) * lda + k0 + kgl * 8),
                (__attribute__((address_space(3))) void*)(Al[buf] + s * 8), 16, 0, 0);
            __builtin_amdgcn_global_load_lds(
                (const __attribute__((address_space(1))) void*)(Bt + (long)(n0 + row) * ldb + k0 + kgl * 8),
                (__attribute__((address_space(3))) void*)(Bl[buf] + s * 8), 16, 0, 0);
        }
    };

    stage(0, 0);
    int cur = 0;
    for (int k0 = 0; k0 < K; k0 += 32) {
        if (k0 + 32 < K) {
            stage(cur ^ 1, k0 + 32);                       // 4 loads/thread in flight
            asm volatile("s_waitcnt vmcnt(4)" ::: "memory"); // wait only current tile
        } else {
            asm volatile("s_waitcnt vmcnt(0)" ::: "memory");
        }
        __builtin_amdgcn_s_barrier();
        asm volatile("" ::: "memory");
        short8 af[4], bf[4];
        #pragma unroll
        for (int m = 0; m < 4; ++m) {
            int row = wr * 64 + m * 16 + l15;
            af[m] = *(const short8*)&Al[cur][row * 32 + (kq ^ ((row >> 1) & 3)) * 8];
        }
        #pragma unroll
        for (int n = 0; n < 4; ++n) {
            int row = wc * 64 + n * 16 + l15;
            bf[n] = *(const short8*)&Bl[cur][row * 32 + (kq ^ ((row >> 1) & 3)) * 8];
        }
        #pragma unroll
        for (int m = 0; m < 4; ++m)
            #pragma unroll
            for (int n = 0; n < 4; ++n)
                acc[m][n] = __builtin_amdgcn_mfma_f32_16x16x32_bf16(af[m], bf[n], acc[m][n], 0, 0, 0);
        asm volatile("" ::: "memory");
        __builtin_amdgcn_s_barrier();   // all waves done reading buf[cur] before restage
        asm volatile("" ::: "memory");
        cur ^= 1;
    }
    #pragma unroll
    for (int m = 0; m < 4; ++m) {
        #pragma unroll
        for (int n = 0; n < 4; ++n) {
            #pragma unroll
            for (int r = 0; r < 4; ++r) {
                int row = m0 + wr * 64 + m * 16 + kq * 4 + r;
                int col = n0 + wc * 64 + n * 16 + l15;
                float v = acc[m][n][r];
                if (EPI == 1) {
                    v += bias[col];
                    v = (v > 20.f) ? v : log1pf(__expf(v));
                }
                if (OBF) Cb[(long)row * N + col] = f2bf_bits(v);
                else     Cf[(long)row * N + col] = v;
            }
        }
    }
}

// ---------------- bf16 MFMA GEMM 128x64, 2-phase double-buffered (vmcnt(3)) ----------
template <int EPI, int OBF>
__global__ __launch_bounds__(256) void gemm_mfma64_kernel(const ushort* __restrict__ A,
                                                          const ushort* __restrict__ Bt,
                                                          const float* __restrict__ bias,
                                                          float* __restrict__ Cf,
                                                          ushort* __restrict__ Cb,
                                                          int M, int N, int K)
{
    int lin = blockIdx.y * gridDim.x + blockIdx.x;
    int cpx = (gridDim.x * gridDim.y) >> 3;
    lin = (lin & 7) * cpx + (lin >> 3);
    int bx = lin % gridDim.x, by = lin / gridDim.x;
    __shared__ __align__(16) ushort Al[2][128 * 32];
    __shared__ __align__(16) ushort Bl[2][64 * 32];
    int tid = threadIdx.x;
    int lane = tid & 63;
    int w = tid >> 6, wr = w >> 1, wc = w & 1;
    int m0 = by * 128, n0 = bx * 64;
    f32x4 acc[4][2];
    #pragma unroll
    for (int m = 0; m < 4; ++m)
        #pragma unroll
        for (int n = 0; n < 2; ++n) acc[m][n] = (f32x4){0.f, 0.f, 0.f, 0.f};
    int l15 = lane & 15, kq = lane >> 4;

    auto stage = [&](int buf, int k0) {
        #pragma unroll
        for (int i = 0; i < 2; ++i) {
            int s = i * 256 + tid;
            int row = s >> 2, kg = s & 3;
            int kgl = kg ^ ((row >> 1) & 3);
            __builtin_amdgcn_global_load_lds(
                (const __attribute__((address_space(1))) void*)(A + (long)(m0 + row) * K + k0 + kgl * 8),
                (__attribute__((address_space(3))) void*)(Al[buf] + s * 8), 16, 0, 0);
        }
        {
            int s = tid;
            int row = s >> 2, kg = s & 3;
            int kgl = kg ^ ((row >> 1) & 3);
            __builtin_amdgcn_global_load_lds(
                (const __attribute__((address_space(1))) void*)(Bt + (long)(n0 + row) * K + k0 + kgl * 8),
                (__attribute__((address_space(3))) void*)(Bl[buf] + s * 8), 16, 0, 0);
        }
    };

    stage(0, 0);
    int cur = 0;
    for (int k0 = 0; k0 < K; k0 += 32) {
        if (k0 + 32 < K) {
            stage(cur ^ 1, k0 + 32);
            asm volatile("s_waitcnt vmcnt(3)" ::: "memory");
        } else {
            asm volatile("s_waitcnt vmcnt(0)" ::: "memory");
        }
        __builtin_amdgcn_s_barrier();
        asm volatile("" ::: "memory");
        short8 af[4], bf[2];
        #pragma unroll
        for (int m = 0; m < 4; ++m) {
            int row = wr * 64 + m * 16 + l15;
            af[m] = *(const short8*)&Al[cur][row * 32 + (kq ^ ((row >> 1) & 3)) * 8];
        }
        #pragma unroll
        for (int n = 0; n < 2; ++n) {
            int row = wc * 32 + n * 16 + l15;
            bf[n] = *(const short8*)&Bl[cur][row * 32 + (kq ^ ((row >> 1) & 3)) * 8];
        }
        #pragma unroll
        for (int m = 0; m < 4; ++m)
            #pragma unroll
            for (int n = 0; n < 2; ++n)
                acc[m][n] = __builtin_amdgcn_mfma_f32_16x16x32_bf16(af[m], bf[n], acc[m][n], 0, 0, 0);
        asm volatile("" ::: "memory");
        __builtin_amdgcn_s_barrier();
        asm volatile("" ::: "memory");
        cur ^= 1;
    }
    #pragma unroll
    for (int m = 0; m < 4; ++m) {
        #pragma unroll
        for (int n = 0; n < 2; ++n) {
            #pragma unroll
            for (int r = 0; r < 4; ++r) {
                int row = m0 + wr * 64 + m * 16 + kq * 4 + r;
                int col = n0 + wc * 32 + n * 16 + l15;
                float v = acc[m][n][r];
                if (EPI == 1) {
                    v += bias[col];
                    v = (v > 20.f) ? v : log1pf(__expf(v));
                }
                if (OBF) Cb[(long)row * N + col] = f2bf_bits(v);
                else     Cf[(long)row * N + col] = v;
            }
        }
    }
}

// -------- out_proj split-K reduce: out = sum_k Ppart[k] + resid --------
__global__ __launch_bounds__(256) void reduce_out_kernel(const float* __restrict__ Ppart,
                                                         const float* __restrict__ resid,
                                                         float* __restrict__ out)
{
    long i = (long)blockIdx.x * 256 + threadIdx.x;
    const long STRIDE = (long)NTOK * D_MODEL / 4;
    float4 s = ((const float4*)Ppart)[i];
    #pragma unroll
    for (int k = 1; k < OP_SPLITK; ++k) {
        float4 p = ((const float4*)Ppart)[k * STRIDE + i];
        s.x += p.x; s.y += p.y; s.z += p.z; s.w += p.w;
    }
    float4 r = ((const float4*)resid)[i];
    s.x += r.x; s.y += r.y; s.z += r.z; s.w += r.w;
    ((float4*)out)[i] = s;
}

// -------- split-K bf16 MFMA GEMM for xpj (single-buffered; non-uniform load counts) ---
__global__ __launch_bounds__(256) void gemm4_mfma_kernel(const ushort* __restrict__ A,
                                                         const ushort* __restrict__ Bt,
                                                         float* __restrict__ Ppart,
                                                         int M, int K)
{
    __shared__ __align__(16) ushort Al[64 * 32];
    __shared__ __align__(16) ushort Bl[160 * 32];
    int tid = threadIdx.x;
    int lane = tid & 63;
    int w = tid >> 6, wr = w >> 1, wc = w & 1;
    int sk = blockIdx.x;
    int m0 = blockIdx.y * 64;
    int kbase = sk * (K / SPLITK);
    f32x4 acc[2][5];
    #pragma unroll
    for (int m = 0; m < 2; ++m)
        #pragma unroll
        for (int n = 0; n < 5; ++n) acc[m][n] = (f32x4){0.f, 0.f, 0.f, 0.f};
    int l15 = lane & 15, kq = lane >> 4;

    for (int ks = 0; ks < K / SPLITK; ks += 32) {
        int k0 = kbase + ks;
        {
            int s = tid;
            int row = s >> 2, kg = s & 3;
            int kgl = kg ^ ((row >> 1) & 3);
            __builtin_amdgcn_global_load_lds(
                (const __attribute__((address_space(1))) void*)(A + (long)(m0 + row) * K + k0 + kgl * 8),
                (__attribute__((address_space(3))) void*)(Al + s * 8), 16, 0, 0);
        }
        #pragma unroll
        for (int i = 0; i < 3; ++i) {
            int s = i * 256 + tid;
            if (s < 640) {
                int row = s >> 2, kg = s & 3;
                int kgl = kg ^ ((row >> 1) & 3);
                __builtin_amdgcn_global_load_lds(
                    (const __attribute__((address_space(1))) void*)(Bt + (long)row * K + k0 + kgl * 8),
                    (__attribute__((address_space(3))) void*)(Bl + s * 8), 16, 0, 0);
            }
        }
        __syncthreads();
        short8 af[2], bf[5];
        #pragma unroll
        for (int m = 0; m < 2; ++m) {
            int row = wr * 32 + m * 16 + l15;
            af[m] = *(const short8*)&Al[row * 32 + (kq ^ ((row >> 1) & 3)) * 8];
        }
        #pragma unroll
        for (int n = 0; n < 5; ++n) {
            int row = wc * 80 + n * 16 + l15;
            bf[n] = *(const short8*)&Bl[row * 32 + (kq ^ ((row >> 1) & 3)) * 8];
        }
        #pragma unroll
        for (int m = 0; m < 2; ++m)
            #pragma unroll
            for (int n = 0; n < 5; ++n)
                acc[m][n] = __builtin_amdgcn_mfma_f32_16x16x32_bf16(af[m], bf[n], acc[m][n], 0, 0, 0);
        __syncthreads();
    }
    float* P = Ppart + (long)sk * M * XPJ_N;
    #pragma unroll
    for (int m = 0; m < 2; ++m) {
        #pragma unroll
        for (int n = 0; n < 5; ++n) {
            #pragma unroll
            for (int r = 0; r < 4; ++r) {
                int row = m0 + wr * 32 + m * 16 + kq * 4 + r;
                int col = wc * 80 + n * 16 + l15;
                P[(long)row * XPJ_N + col] = acc[m][n][r];
            }
        }
    }
}

// -------- reduce split-K partials → xpj f32 + dt_r bf16 --------
__global__ __launch_bounds__(256) void reduce_xpj_kernel(const float* __restrict__ Ppart,
                                                         float* __restrict__ xpj,
                                                         ushort* __restrict__ dtr)
{
    long i = (long)blockIdx.x * 256 + threadIdx.x;
    float s = 0.f;
    #pragma unroll
    for (int k = 0; k < SPLITK; ++k) s += Ppart[k * (long)NTOK * XPJ_N + i];
    xpj[i] = s;
    int col = (int)(i % XPJ_N);
    long row = i / XPJ_N;
    if (col < DT_RANK) dtr[row * DT_RANK + col] = f2bf_bits(s);
}

// ---------------- depthwise causal conv (width 4) + bias + SiLU; bf16 in/out ----------
__global__ __launch_bounds__(256) void conv_silu_kernel(const ushort* __restrict__ xzb,
                                                        const float* __restrict__ cw,
                                                        const float* __restrict__ cb,
                                                        ushort* __restrict__ xbb)
{
    long i = (long)blockIdx.x * 256 + threadIdx.x;  // over NTOK*D_INNER
    int d = (int)(i & (D_INNER - 1));
    long tok = i >> 11;
    int l = (int)(tok & (SEQLEN - 1));
    float w0 = cw[d * 4 + 0], w1 = cw[d * 4 + 1], w2 = cw[d * 4 + 2], w3 = cw[d * 4 + 3];
    float acc = cb[d];
    acc += bf2f(xzb[tok * NPROJ + d]) * w3;
    if (l >= 1) acc += bf2f(xzb[(tok - 1) * NPROJ + d]) * w2;
    if (l >= 2) acc += bf2f(xzb[(tok - 2) * NPROJ + d]) * w1;
    if (l >= 3) acc += bf2f(xzb[(tok - 3) * NPROJ + d]) * w0;
    float v = acc * sigmoidf_(acc);
    xbb[i] = f2bf_bits(v);
}

// ======================= chunked selective scan: 1 lane/channel, CHUNK=16 =============
__global__ __launch_bounds__(256) void scan_partial_kernel(const ushort* __restrict__ deltab,
                                                           const ushort* __restrict__ xbb,
                                                           const float* __restrict__ xpj,
                                                           const float* __restrict__ A_log,
                                                           float* __restrict__ Pout,
                                                           float* __restrict__ Hout)
{
    __shared__ float bc[CHUNK][32];
    int blk = blockIdx.x;
    int db = blk & 7;
    int c  = (blk >> 3) & (NCHUNK - 1);
    int b  = blk >> (3 + LOG2_NCHUNK);
    int d  = db * 256 + threadIdx.x;
    long tok0 = (long)b * SEQLEN + c * CHUNK;
    for (int i = threadIdx.x; i < CHUNK * 32; i += 256) {
        int t = i >> 5, cc = i & 31;
        bc[t][cc] = xpj[(tok0 + t) * XPJ_N + DT_RANK + cc];
    }
    float a[16], h[16];
    #pragma unroll
    for (int q = 0; q < 4; ++q) {
        float4 al = *(const float4*)&A_log[d * D_STATE + q * 4];
        a[q*4+0] = -__expf(al.x) * LOG2E;
        a[q*4+1] = -__expf(al.y) * LOG2E;
        a[q*4+2] = -__expf(al.z) * LOG2E;
        a[q*4+3] = -__expf(al.w) * LOG2E;
    }
    #pragma unroll
    for (int n = 0; n < 16; ++n) h[n] = 0.f;
    float cum = 0.f;
    const ushort* dp = deltab + tok0 * D_INNER + d;
    const ushort* xp = xbb + tok0 * D_INNER + d;
    __syncthreads();
    for (int t = 0; t < CHUNK; ++t) {
        float dl = bf2f(dp[(long)t * D_INNER]);
        float x  = bf2f(xp[(long)t * D_INNER]);
        float ux = dl * x;
        cum += dl;
        #pragma unroll
        for (int q = 0; q < 4; ++q) {
            float4 Bv = *(const float4*)&bc[t][q * 4];
            h[q*4+0] = exp2f(dl * a[q*4+0]) * h[q*4+0] + ux * Bv.x;
            h[q*4+1] = exp2f(dl * a[q*4+1]) * h[q*4+1] + ux * Bv.y;
            h[q*4+2] = exp2f(dl * a[q*4+2]) * h[q*4+2] + ux * Bv.z;
            h[q*4+3] = exp2f(dl * a[q*4+3]) * h[q*4+3] + ux * Bv.w;
        }
    }
    long chbase = ((long)(b * NCHUNK + c) * D_INNER + d) * D_STATE;
    #pragma unroll
    for (int q = 0; q < 4; ++q) {
        float4 pv = {exp2f(a[q*4+0] * cum), exp2f(a[q*4+1] * cum),
                     exp2f(a[q*4+2] * cum), exp2f(a[q*4+3] * cum)};
        *(float4*)&Pout[chbase + q * 4] = pv;
        float4 hv = {h[q*4+0], h[q*4+1], h[q*4+2], h[q*4+3]};
        *(float4*)&Hout[chbase + q * 4] = hv;
    }
}

__global__ __launch_bounds__(256) void scan_chunkscan_kernel(const float* __restrict__ P,
                                                             const float* __restrict__ H,
                                                             float* __restrict__ hinit)
{
    long i = (long)blockIdx.x * 256 + threadIdx.x;  // over BATCH*D_INNER*D_STATE
    int n = (int)(i & (D_STATE - 1));
    int d = (int)((i >> 4) & (D_INNER - 1));
    int b = (int)(i >> 15);
    float h = 0.f;
    for (int c = 0; c < NCHUNK; ++c) {
        long o = ((((long)b * NCHUNK + c) * D_INNER + d) * D_STATE) + n;
        hinit[o] = h;
        h = P[o] * h + H[o];
    }
}

__global__ __launch_bounds__(256) void scan_final_kernel(const ushort* __restrict__ deltab,
                                                         const ushort* __restrict__ xbb,
                                                         const float* __restrict__ xpj,
                                                         const ushort* __restrict__ xzb,
                                                         const float* __restrict__ A_log,
                                                         const float* __restrict__ Dp,
                                                         const float* __restrict__ hinit,
                                                         ushort* __restrict__ yb)
{
    __shared__ float bc[CHUNK][32];
    int blk = blockIdx.x;
    int db = blk & 7;
    int c  = (blk >> 3) & (NCHUNK - 1);
    int b  = blk >> (3 + LOG2_NCHUNK);
    int d  = db * 256 + threadIdx.x;
    long tok0 = (long)b * SEQLEN + c * CHUNK;
    for (int i = threadIdx.x; i < CHUNK * 32; i += 256) {
        int t = i >> 5, cc = i & 31;
        bc[t][cc] = xpj[(tok0 + t) * XPJ_N + DT_RANK + cc];
    }
    float a[16], h[16];
    #pragma unroll
    for (int q = 0; q < 4; ++q) {
        float4 al = *(const float4*)&A_log[d * D_STATE + q * 4];
        a[q*4+0] = -__expf(al.x) * LOG2E;
        a[q*4+1] = -__expf(al.y) * LOG2E;
        a[q*4+2] = -__expf(al.z) * LOG2E;
        a[q*4+3] = -__expf(al.w) * LOG2E;
    }
    long chbase = ((long)(b * NCHUNK + c) * D_INNER + d) * D_STATE;
    #pragma unroll
    for (int q = 0; q < 4; ++q) {
        float4 hv = *(const float4*)&hinit[chbase + q * 4];
        h[q*4+0] = hv.x; h[q*4+1] = hv.y; h[q*4+2] = hv.z; h[q*4+3] = hv.w;
    }
    float dpar = Dp[d];
    const ushort* dp = deltab + tok0 * D_INNER + d;
    const ushort* xp = xbb + tok0 * D_INNER + d;
    const ushort* zp = xzb + tok0 * NPROJ + D_INNER + d;
    ushort* yp = yb + tok0 * D_INNER + d;
    __syncthreads();
    for (int t = 0; t < CHUNK; ++t) {
        float dl = bf2f(dp[(long)t * D_INNER]);
        float x  = bf2f(xp[(long)t * D_INNER]);
        float z  = bf2f(zp[(long)t * NPROJ]);
        float ux = dl * x;
        float y = 0.f;
        #pragma unroll
        for (int q = 0; q < 4; ++q) {
            float4 Bv = *(const float4*)&bc[t][q * 4];
            float4 Cv = *(const float4*)&bc[t][16 + q * 4];
            h[q*4+0] = exp2f(dl * a[q*4+0]) * h[q*4+0] + ux * Bv.x;
            h[q*4+1] = exp2f(dl * a[q*4+1]) * h[q*4+1] + ux * Bv.y;
            h[q*4+2] = exp2f(dl * a[q*4+2]) * h[q*4+2] + ux * Bv.z;
            h[q*4+3] = exp2f(dl * a[q*4+3]) * h[q*4+3] + ux * Bv.w;
            y += h[q*4+0] * Cv.x + h[q*4+1] * Cv.y + h[q*4+2] * Cv.z + h[q*4+3] * Cv.w;
        }
        y += x * dpar;
        yp[(long)t * D_INNER] = f2bf_bits(y * (z * sigmoidf_(z)));
    }
}

extern "C" void kernel_launch(void* const* d_in, const int* in_sizes, int n_in,
                              void* d_out, int out_size, void* d_ws, size_t ws_size,
                              hipStream_t stream) {
    const float* x         = (const float*)d_in[0];
    const float* ln_gamma  = (const float*)d_in[1];
    const float* ln_beta   = (const float*)d_in[2];
    const float* in_proj_w = (const float*)d_in[3];
    const float* conv_w    = (const float*)d_in[4];
    const float* conv_b    = (const float*)d_in[5];
    const float* x_proj_w  = (const float*)d_in[6];
    const float* dt_proj_w = (const float*)d_in[7];
    const float* dt_proj_b = (const float*)d_in[8];
    const float* A_log     = (const float*)d_in[9];
    const float* D_param   = (const float*)d_in[10];
    const float* out_proj_w= (const float*)d_in[11];
    float* out = (float*)d_out;

    // Clean disjoint arena (d_ws ≈ 268 MB; used ≈ 156 MB).
    float* p = (float*)d_ws;
    ushort* hb      = (ushort*)p; p += 1048576;   // [2048][1024] bf16
    ushort* W2T     = (ushort*)p; p += 2097152;   // [4096][1024] bf16
    ushort* W7T     = (ushort*)p; p += 1048576;   // [1024][2048] bf16
    ushort* XPT     = (ushort*)p; p += 163840;    // [160][2048] bf16
    ushort* DTT     = (ushort*)p; p += 131072;    // [2048][128] bf16
    ushort* xz_bf16 = (ushort*)p; p += 4194304;   // [2048 tok][4096] bf16
    ushort* xb_bf16 = (ushort*)p; p += 2097152;   // [tok][2048] bf16
    float*  xpj     = p;          p += 327680;    // [tok][160] f32
    ushort* dtr     = (ushort*)p; p += 131072;    // [tok][128] bf16
    ushort* delta_bf16 = (ushort*)p; p += 2097152;// [tok][2048] bf16
    float*  Ppart   = p;          p += 2621440;   // gemm4 partials [8][2048][160]
    float*  Pbuf    = p;          p += 4194304;   // scan P  [B][64][2048][16]
    float*  Hbuf    = p;          p += 4194304;   // scan H
    float*  hinit   = p;          p += 4194304;
    ushort* y_bf16  = (ushort*)p; p += 2097152;   // [tok][2048] bf16 = 4,194,304 ushorts
    float*  PpartO  = p;          p += 8388608;   // out_proj partials [4][2048][1024]

    // 0. all four weight transposes, one dispatch
    transpose_all_kernel<<<1696, 256, 0, stream>>>(
        in_proj_w, W2T, out_proj_w, W7T, x_proj_w, XPT, dt_proj_w, DTT);

    // 1. LayerNorm → bf16
    ln_kernel<<<NTOK, 256, 0, stream>>>(x, ln_gamma, ln_beta, hb);

    // 2. xz = h @ in_proj_w (MFMA 2-phase, bf16 out, XCD swizzle) [2048,1024]x[1024,4096]
    gemm_mfma_kernel<0, 1><<<dim3(NPROJ / 128, NTOK / 128), 256, 0, stream>>>(
        hb, W2T, nullptr, nullptr, xz_bf16, NTOK, NPROJ, D_MODEL, D_MODEL, D_MODEL);

    // 3. conv4 + bias + SiLU (bf16 in/out)
    conv_silu_kernel<<<(NTOK * D_INNER) / 256, 256, 0, stream>>>(
        xz_bf16, conv_w, conv_b, xb_bf16);

    // 4. xpj partials (split-K MFMA) then reduce → xpj f32 + dtr bf16
    gemm4_mfma_kernel<<<dim3(SPLITK, NTOK / 64), 256, 0, stream>>>(
        xb_bf16, XPT, Ppart, NTOK, D_INNER);
    reduce_xpj_kernel<<<(NTOK * XPJ_N) / 256, 256, 0, stream>>>(Ppart, xpj, dtr);

    // 5. delta = softplus(dt_r @ dt_proj_w + b) (MFMA 128x64 2-phase, bf16 out)
    gemm_mfma64_kernel<1, 1><<<dim3(D_INNER / 64, NTOK / 128), 256, 0, stream>>>(
        dtr, DTT, dt_proj_b, nullptr, delta_bf16, NTOK, D_INNER, DT_RANK);

    // 6. chunked selective scan (1 lane/channel, CHUNK=16, LDS-staged B/C)
    scan_partial_kernel<<<BATCH * NCHUNK * 8, 256, 0, stream>>>(
        delta_bf16, xb_bf16, xpj, A_log, Pbuf, Hbuf);
    scan_chunkscan_kernel<<<(BATCH * D_INNER * D_STATE) / 256, 256, 0, stream>>>(
        Pbuf, Hbuf, hinit);
    scan_final_kernel<<<BATCH * NCHUNK * 8, 256, 0, stream>>>(
        delta_bf16, xb_bf16, xpj, xz_bf16, A_log, D_param, hinit, y_bf16);

    // 7. out_proj split-K=4: 2-phase partials then fused reduce+residual
    gemm_mfma_kernel<0, 0><<<dim3(D_MODEL / 128, NTOK / 128, OP_SPLITK), 256, 0, stream>>>(
        y_bf16, W7T, nullptr, PpartO, nullptr, NTOK, D_MODEL, D_INNER / OP_SPLITK,
        D_INNER, D_INNER);
    reduce_out_kernel<<<(NTOK * D_MODEL / 4) / 256, 256, 0, stream>>>(PpartO, x, out);
}

// Round 16
// 183.849 us; speedup vs baseline: 1.1345x; 1.0259x over previous
//
#include <hip/hip_runtime.h>
#include <hip/hip_bf16.h>

#define D_MODEL 1024
#define D_INNER 2048
#define NPROJ   4096   /* 2*D_INNER */
#define D_STATE 16
#define DT_RANK 128
#define XPJ_N   160    /* DT_RANK + 2*D_STATE */
#define SEQLEN  1024
#define BATCH   2
#define NTOK    2048   /* BATCH*SEQLEN */
#define CHUNK   16
#define NCHUNK  (SEQLEN / CHUNK)   /* 64 */
#define LOG2_NCHUNK 6
#define SPLITK  8      /* gemm4 split */
#define OP_SPLITK 4    /* out_proj split */

typedef short short8 __attribute__((ext_vector_type(8)));
typedef float f32x4 __attribute__((ext_vector_type(4)));

__device__ __forceinline__ float sigmoidf_(float x) { return 1.f / (1.f + __expf(-x)); }
__device__ __forceinline__ ushort f2bf_bits(float f) {
    __hip_bfloat16 h = __float2bfloat16(f);
    return *(ushort*)&h;
}
__device__ __forceinline__ float bf2f(ushort u) {
    union { unsigned int i; float f; } v;
    v.i = ((unsigned int)u) << 16;
    return v.f;
}
#define LOG2E 1.44269504088896f

// ---------------- LayerNorm → bf16 output ----------------
__global__ __launch_bounds__(256) void ln_kernel(const float* __restrict__ x,
                                                 const float* __restrict__ g,
                                                 const float* __restrict__ be,
                                                 ushort* __restrict__ hb)
{
    int row = blockIdx.x;
    const float4* xr = (const float4*)(x + (long)row * D_MODEL);
    float4 v = xr[threadIdx.x];
    float s1 = v.x + v.y + v.z + v.w;
    float s2 = v.x*v.x + v.y*v.y + v.z*v.z + v.w*v.w;
    for (int off = 32; off >= 1; off >>= 1) {
        s1 += __shfl_down(s1, off);
        s2 += __shfl_down(s2, off);
    }
    __shared__ float red[8];
    int wid = threadIdx.x >> 6;
    if ((threadIdx.x & 63) == 0) { red[wid] = s1; red[4 + wid] = s2; }
    __syncthreads();
    float mu  = (red[0] + red[1] + red[2] + red[3]) * (1.f / D_MODEL);
    float ex2 = (red[4] + red[5] + red[6] + red[7]) * (1.f / D_MODEL);
    float inv = rsqrtf(ex2 - mu * mu + 1e-5f);
    float4 g4 = ((const float4*)g)[threadIdx.x];
    float4 b4 = ((const float4*)be)[threadIdx.x];
    ushort4 o;
    o.x = f2bf_bits((v.x - mu) * inv * g4.x + b4.x);
    o.y = f2bf_bits((v.y - mu) * inv * g4.y + b4.y);
    o.z = f2bf_bits((v.z - mu) * inv * g4.z + b4.z);
    o.w = f2bf_bits((v.w - mu) * inv * g4.w + b4.w);
    *(ushort4*)(hb + (long)row * D_MODEL + threadIdx.x * 4) = o;
}

// ---------------- batched f32 [R][C] → bf16 [C][R] transpose (4 weights, 1 dispatch) --
__device__ __forceinline__ void transpose_tile(const float* __restrict__ in,
                                               ushort* __restrict__ out,
                                               int R, int C, int cx, int ry)
{
    __shared__ float tile[64][65];
    int c0 = cx * 64, r0 = ry * 64;
    #pragma unroll
    for (int i = 0; i < 16; ++i) {
        int idx = threadIdx.x + i * 256;
        int r = idx >> 6, c = idx & 63;
        tile[r][c] = (r0 + r < R && c0 + c < C) ? in[(long)(r0 + r) * C + (c0 + c)] : 0.f;
    }
    __syncthreads();
    #pragma unroll
    for (int i = 0; i < 16; ++i) {
        int idx = threadIdx.x + i * 256;
        int cc = idx >> 6, rr = idx & 63;
        if (c0 + cc < C && r0 + rr < R)
            out[(long)(c0 + cc) * R + (r0 + rr)] = f2bf_bits(tile[rr][cc]);
    }
}

__global__ __launch_bounds__(256) void transpose_all_kernel(const float* __restrict__ w2,
                                                            ushort* __restrict__ W2T,
                                                            const float* __restrict__ w7,
                                                            ushort* __restrict__ W7T,
                                                            const float* __restrict__ xp,
                                                            ushort* __restrict__ XPT,
                                                            const float* __restrict__ dt,
                                                            ushort* __restrict__ DTT)
{
    int idx = blockIdx.x;
    if (idx < 1024) {
        transpose_tile(w2, W2T, D_MODEL, NPROJ, idx & 63, idx >> 6);
    } else if (idx < 1536) {
        int rel = idx - 1024;
        transpose_tile(w7, W7T, D_INNER, D_MODEL, rel & 15, rel >> 4);
    } else if (idx < 1632) {
        int rel = idx - 1536;
        transpose_tile(xp, XPT, D_INNER, XPJ_N, rel % 3, rel / 3);
    } else {
        int rel = idx - 1632;
        transpose_tile(dt, DTT, DT_RANK, D_INNER, rel & 31, rel >> 5);
    }
}

// ---------------- bf16 MFMA GEMM 128x128, 2-phase double-buffered pipeline -----------
// OBF 0: f32 to Cf ; OBF 1: bf16 to Cb. Split-K via blockIdx.z (offsets both outputs).
template <int EPI, int OBF>
__global__ __launch_bounds__(256) void gemm_mfma_kernel(const ushort* __restrict__ A,
                                                        const ushort* __restrict__ Bt,
                                                        const float* __restrict__ bias,
                                                        float* __restrict__ Cf,
                                                        ushort* __restrict__ Cb,
                                                        int M, int N, int K, int lda, int ldb)
{
    long zoff = (long)blockIdx.z;
    A  += zoff * K;
    Bt += zoff * K;
    if (OBF == 0) Cf += zoff * (long)M * N;
    else          Cb += zoff * (long)M * N;
    int lin = blockIdx.y * gridDim.x + blockIdx.x;
    int cpx = (gridDim.x * gridDim.y) >> 3;
    lin = (lin & 7) * cpx + (lin >> 3);
    int bx = lin % gridDim.x, by = lin / gridDim.x;
    __shared__ __align__(16) ushort Al[2][128 * 32];
    __shared__ __align__(16) ushort Bl[2][128 * 32];
    int tid = threadIdx.x;
    int lane = tid & 63;
    int w = tid >> 6, wr = w >> 1, wc = w & 1;
    int m0 = by * 128, n0 = bx * 128;
    f32x4 acc[4][4];
    #pragma unroll
    for (int m = 0; m < 4; ++m)
        #pragma unroll
        for (int n = 0; n < 4; ++n) acc[m][n] = (f32x4){0.f, 0.f, 0.f, 0.f};
    int l15 = lane & 15, kq = lane >> 4;

    auto stage = [&](int buf, int k0) {
        #pragma unroll
        for (int i = 0; i < 2; ++i) {
            int s = i * 256 + tid;
            int row = s >> 2, kg = s & 3;
            int kgl = kg ^ ((row >> 1) & 3);
            __builtin_amdgcn_global_load_lds(
                (const __attribute__((address_space(1))) void*)(A + (long)(m0 + row) * lda + k0 + kgl * 8),
                (__attribute__((address_space(3))) void*)(Al[buf] + s * 8), 16, 0, 0);
            __builtin_amdgcn_global_load_lds(
                (const __attribute__((address_space(1))) void*)(Bt + (long)(n0 + row) * ldb + k0 + kgl * 8),
                (__attribute__((address_space(3))) void*)(Bl[buf] + s * 8), 16, 0, 0);
        }
    };

    stage(0, 0);
    int cur = 0;
    for (int k0 = 0; k0 < K; k0 += 32) {
        if (k0 + 32 < K) {
            stage(cur ^ 1, k0 + 32);
            asm volatile("s_waitcnt vmcnt(4)" ::: "memory");
        } else {
            asm volatile("s_waitcnt vmcnt(0)" ::: "memory");
        }
        __builtin_amdgcn_s_barrier();
        asm volatile("" ::: "memory");
        short8 af[4], bf[4];
        #pragma unroll
        for (int m = 0; m < 4; ++m) {
            int row = wr * 64 + m * 16 + l15;
            af[m] = *(const short8*)&Al[cur][row * 32 + (kq ^ ((row >> 1) & 3)) * 8];
        }
        #pragma unroll
        for (int n = 0; n < 4; ++n) {
            int row = wc * 64 + n * 16 + l15;
            bf[n] = *(const short8*)&Bl[cur][row * 32 + (kq ^ ((row >> 1) & 3)) * 8];
        }
        #pragma unroll
        for (int m = 0; m < 4; ++m)
            #pragma unroll
            for (int n = 0; n < 4; ++n)
                acc[m][n] = __builtin_amdgcn_mfma_f32_16x16x32_bf16(af[m], bf[n], acc[m][n], 0, 0, 0);
        asm volatile("" ::: "memory");
        __builtin_amdgcn_s_barrier();
        asm volatile("" ::: "memory");
        cur ^= 1;
    }
    #pragma unroll
    for (int m = 0; m < 4; ++m) {
        #pragma unroll
        for (int n = 0; n < 4; ++n) {
            #pragma unroll
            for (int r = 0; r < 4; ++r) {
                int row = m0 + wr * 64 + m * 16 + kq * 4 + r;
                int col = n0 + wc * 64 + n * 16 + l15;
                float v = acc[m][n][r];
                if (EPI == 1) {
                    v += bias[col];
                    v = (v > 20.f) ? v : log1pf(__expf(v));
                }
                if (OBF) Cb[(long)row * N + col] = f2bf_bits(v);
                else     Cf[(long)row * N + col] = v;
            }
        }
    }
}

// ---------------- bf16 MFMA GEMM 128x64, 2-phase double-buffered (vmcnt(3)) ----------
template <int EPI, int OBF>
__global__ __launch_bounds__(256) void gemm_mfma64_kernel(const ushort* __restrict__ A,
                                                          const ushort* __restrict__ Bt,
                                                          const float* __restrict__ bias,
                                                          float* __restrict__ Cf,
                                                          ushort* __restrict__ Cb,
                                                          int M, int N, int K)
{
    int lin = blockIdx.y * gridDim.x + blockIdx.x;
    int cpx = (gridDim.x * gridDim.y) >> 3;
    lin = (lin & 7) * cpx + (lin >> 3);
    int bx = lin % gridDim.x, by = lin / gridDim.x;
    __shared__ __align__(16) ushort Al[2][128 * 32];
    __shared__ __align__(16) ushort Bl[2][64 * 32];
    int tid = threadIdx.x;
    int lane = tid & 63;
    int w = tid >> 6, wr = w >> 1, wc = w & 1;
    int m0 = by * 128, n0 = bx * 64;
    f32x4 acc[4][2];
    #pragma unroll
    for (int m = 0; m < 4; ++m)
        #pragma unroll
        for (int n = 0; n < 2; ++n) acc[m][n] = (f32x4){0.f, 0.f, 0.f, 0.f};
    int l15 = lane & 15, kq = lane >> 4;

    auto stage = [&](int buf, int k0) {
        #pragma unroll
        for (int i = 0; i < 2; ++i) {
            int s = i * 256 + tid;
            int row = s >> 2, kg = s & 3;
            int kgl = kg ^ ((row >> 1) & 3);
            __builtin_amdgcn_global_load_lds(
                (const __attribute__((address_space(1))) void*)(A + (long)(m0 + row) * K + k0 + kgl * 8),
                (__attribute__((address_space(3))) void*)(Al[buf] + s * 8), 16, 0, 0);
        }
        {
            int s = tid;
            int row = s >> 2, kg = s & 3;
            int kgl = kg ^ ((row >> 1) & 3);
            __builtin_amdgcn_global_load_lds(
                (const __attribute__((address_space(1))) void*)(Bt + (long)(n0 + row) * K + k0 + kgl * 8),
                (__attribute__((address_space(3))) void*)(Bl[buf] + s * 8), 16, 0, 0);
        }
    };

    stage(0, 0);
    int cur = 0;
    for (int k0 = 0; k0 < K; k0 += 32) {
        if (k0 + 32 < K) {
            stage(cur ^ 1, k0 + 32);
            asm volatile("s_waitcnt vmcnt(3)" ::: "memory");
        } else {
            asm volatile("s_waitcnt vmcnt(0)" ::: "memory");
        }
        __builtin_amdgcn_s_barrier();
        asm volatile("" ::: "memory");
        short8 af[4], bf[2];
        #pragma unroll
        for (int m = 0; m < 4; ++m) {
            int row = wr * 64 + m * 16 + l15;
            af[m] = *(const short8*)&Al[cur][row * 32 + (kq ^ ((row >> 1) & 3)) * 8];
        }
        #pragma unroll
        for (int n = 0; n < 2; ++n) {
            int row = wc * 32 + n * 16 + l15;
            bf[n] = *(const short8*)&Bl[cur][row * 32 + (kq ^ ((row >> 1) & 3)) * 8];
        }
        #pragma unroll
        for (int m = 0; m < 4; ++m)
            #pragma unroll
            for (int n = 0; n < 2; ++n)
                acc[m][n] = __builtin_amdgcn_mfma_f32_16x16x32_bf16(af[m], bf[n], acc[m][n], 0, 0, 0);
        asm volatile("" ::: "memory");
        __builtin_amdgcn_s_barrier();
        asm volatile("" ::: "memory");
        cur ^= 1;
    }
    #pragma unroll
    for (int m = 0; m < 4; ++m) {
        #pragma unroll
        for (int n = 0; n < 2; ++n) {
            #pragma unroll
            for (int r = 0; r < 4; ++r) {
                int row = m0 + wr * 64 + m * 16 + kq * 4 + r;
                int col = n0 + wc * 32 + n * 16 + l15;
                float v = acc[m][n][r];
                if (EPI == 1) {
                    v += bias[col];
                    v = (v > 20.f) ? v : log1pf(__expf(v));
                }
                if (OBF) Cb[(long)row * N + col] = f2bf_bits(v);
                else     Cf[(long)row * N + col] = v;
            }
        }
    }
}

// -------- out_proj split-K reduce (bf16 partials): out = sum_k Ppart[k] + resid ------
__global__ __launch_bounds__(256) void reduce_out_kernel(const ushort* __restrict__ Ppart,
                                                         const float* __restrict__ resid,
                                                         float* __restrict__ out)
{
    long i = (long)blockIdx.x * 256 + threadIdx.x;   // over NTOK*D_MODEL/4
    const long STRIDE = (long)NTOK * D_MODEL;
    float4 s;
    ushort4 p0 = ((const ushort4*)Ppart)[i];
    s.x = bf2f(p0.x); s.y = bf2f(p0.y); s.z = bf2f(p0.z); s.w = bf2f(p0.w);
    #pragma unroll
    for (int k = 1; k < OP_SPLITK; ++k) {
        ushort4 pk = ((const ushort4*)(Ppart + k * STRIDE))[i];
        s.x += bf2f(pk.x); s.y += bf2f(pk.y); s.z += bf2f(pk.z); s.w += bf2f(pk.w);
    }
    float4 r = ((const float4*)resid)[i];
    s.x += r.x; s.y += r.y; s.z += r.z; s.w += r.w;
    ((float4*)out)[i] = s;
}

// -------- split-K bf16 MFMA GEMM for xpj (bf16 partials out) --------
__global__ __launch_bounds__(256) void gemm4_mfma_kernel(const ushort* __restrict__ A,
                                                         const ushort* __restrict__ Bt,
                                                         ushort* __restrict__ Ppart,
                                                         int M, int K)
{
    __shared__ __align__(16) ushort Al[64 * 32];
    __shared__ __align__(16) ushort Bl[160 * 32];
    int tid = threadIdx.x;
    int lane = tid & 63;
    int w = tid >> 6, wr = w >> 1, wc = w & 1;
    int sk = blockIdx.x;
    int m0 = blockIdx.y * 64;
    int kbase = sk * (K / SPLITK);
    f32x4 acc[2][5];
    #pragma unroll
    for (int m = 0; m < 2; ++m)
        #pragma unroll
        for (int n = 0; n < 5; ++n) acc[m][n] = (f32x4){0.f, 0.f, 0.f, 0.f};
    int l15 = lane & 15, kq = lane >> 4;

    for (int ks = 0; ks < K / SPLITK; ks += 32) {
        int k0 = kbase + ks;
        {
            int s = tid;
            int row = s >> 2, kg = s & 3;
            int kgl = kg ^ ((row >> 1) & 3);
            __builtin_amdgcn_global_load_lds(
                (const __attribute__((address_space(1))) void*)(A + (long)(m0 + row) * K + k0 + kgl * 8),
                (__attribute__((address_space(3))) void*)(Al + s * 8), 16, 0, 0);
        }
        #pragma unroll
        for (int i = 0; i < 3; ++i) {
            int s = i * 256 + tid;
            if (s < 640) {
                int row = s >> 2, kg = s & 3;
                int kgl = kg ^ ((row >> 1) & 3);
                __builtin_amdgcn_global_load_lds(
                    (const __attribute__((address_space(1))) void*)(Bt + (long)row * K + k0 + kgl * 8),
                    (__attribute__((address_space(3))) void*)(Bl + s * 8), 16, 0, 0);
            }
        }
        __syncthreads();
        short8 af[2], bf[5];
        #pragma unroll
        for (int m = 0; m < 2; ++m) {
            int row = wr * 32 + m * 16 + l15;
            af[m] = *(const short8*)&Al[row * 32 + (kq ^ ((row >> 1) & 3)) * 8];
        }
        #pragma unroll
        for (int n = 0; n < 5; ++n) {
            int row = wc * 80 + n * 16 + l15;
            bf[n] = *(const short8*)&Bl[row * 32 + (kq ^ ((row >> 1) & 3)) * 8];
        }
        #pragma unroll
        for (int m = 0; m < 2; ++m)
            #pragma unroll
            for (int n = 0; n < 5; ++n)
                acc[m][n] = __builtin_amdgcn_mfma_f32_16x16x32_bf16(af[m], bf[n], acc[m][n], 0, 0, 0);
        __syncthreads();
    }
    ushort* P = Ppart + (long)sk * M * XPJ_N;
    #pragma unroll
    for (int m = 0; m < 2; ++m) {
        #pragma unroll
        for (int n = 0; n < 5; ++n) {
            #pragma unroll
            for (int r = 0; r < 4; ++r) {
                int row = m0 + wr * 32 + m * 16 + kq * 4 + r;
                int col = wc * 80 + n * 16 + l15;
                P[(long)row * XPJ_N + col] = f2bf_bits(acc[m][n][r]);
            }
        }
    }
}

// -------- reduce split-K bf16 partials → xpj f32 + dt_r bf16 --------
__global__ __launch_bounds__(256) void reduce_xpj_kernel(const ushort* __restrict__ Ppart,
                                                         float* __restrict__ xpj,
                                                         ushort* __restrict__ dtr)
{
    long i = (long)blockIdx.x * 256 + threadIdx.x;   // over NTOK*XPJ_N
    float s = 0.f;
    #pragma unroll
    for (int k = 0; k < SPLITK; ++k) s += bf2f(Ppart[k * (long)NTOK * XPJ_N + i]);
    xpj[i] = s;
    int col = (int)(i % XPJ_N);
    long row = i / XPJ_N;
    if (col < DT_RANK) dtr[row * DT_RANK + col] = f2bf_bits(s);
}

// ---------------- depthwise causal conv (width 4) + bias + SiLU; bf16 in/out ----------
__global__ __launch_bounds__(256) void conv_silu_kernel(const ushort* __restrict__ xzb,
                                                        const float* __restrict__ cw,
                                                        const float* __restrict__ cb,
                                                        ushort* __restrict__ xbb)
{
    long i = (long)blockIdx.x * 256 + threadIdx.x;  // over NTOK*D_INNER
    int d = (int)(i & (D_INNER - 1));
    long tok = i >> 11;
    int l = (int)(tok & (SEQLEN - 1));
    float w0 = cw[d * 4 + 0], w1 = cw[d * 4 + 1], w2 = cw[d * 4 + 2], w3 = cw[d * 4 + 3];
    float acc = cb[d];
    acc += bf2f(xzb[tok * NPROJ + d]) * w3;
    if (l >= 1) acc += bf2f(xzb[(tok - 1) * NPROJ + d]) * w2;
    if (l >= 2) acc += bf2f(xzb[(tok - 2) * NPROJ + d]) * w1;
    if (l >= 3) acc += bf2f(xzb[(tok - 3) * NPROJ + d]) * w0;
    float v = acc * sigmoidf_(acc);
    xbb[i] = f2bf_bits(v);
}

// ======================= chunked selective scan: 1 lane/channel, CHUNK=16 =============
__global__ __launch_bounds__(256) void scan_partial_kernel(const ushort* __restrict__ deltab,
                                                           const ushort* __restrict__ xbb,
                                                           const float* __restrict__ xpj,
                                                           const float* __restrict__ A_log,
                                                           float* __restrict__ Pout,
                                                           float* __restrict__ Hout)
{
    __shared__ float bc[CHUNK][32];
    int blk = blockIdx.x;
    int db = blk & 7;
    int c  = (blk >> 3) & (NCHUNK - 1);
    int b  = blk >> (3 + LOG2_NCHUNK);
    int d  = db * 256 + threadIdx.x;
    long tok0 = (long)b * SEQLEN + c * CHUNK;
    for (int i = threadIdx.x; i < CHUNK * 32; i += 256) {
        int t = i >> 5, cc = i & 31;
        bc[t][cc] = xpj[(tok0 + t) * XPJ_N + DT_RANK + cc];
    }
    float a[16], h[16];
    #pragma unroll
    for (int q = 0; q < 4; ++q) {
        float4 al = *(const float4*)&A_log[d * D_STATE + q * 4];
        a[q*4+0] = -__expf(al.x) * LOG2E;
        a[q*4+1] = -__expf(al.y) * LOG2E;
        a[q*4+2] = -__expf(al.z) * LOG2E;
        a[q*4+3] = -__expf(al.w) * LOG2E;
    }
    #pragma unroll
    for (int n = 0; n < 16; ++n) h[n] = 0.f;
    float cum = 0.f;
    const ushort* dp = deltab + tok0 * D_INNER + d;
    const ushort* xp = xbb + tok0 * D_INNER + d;
    __syncthreads();
    for (int t = 0; t < CHUNK; ++t) {
        float dl = bf2f(dp[(long)t * D_INNER]);
        float x  = bf2f(xp[(long)t * D_INNER]);
        float ux = dl * x;
        cum += dl;
        #pragma unroll
        for (int q = 0; q < 4; ++q) {
            float4 Bv = *(const float4*)&bc[t][q * 4];
            h[q*4+0] = exp2f(dl * a[q*4+0]) * h[q*4+0] + ux * Bv.x;
            h[q*4+1] = exp2f(dl * a[q*4+1]) * h[q*4+1] + ux * Bv.y;
            h[q*4+2] = exp2f(dl * a[q*4+2]) * h[q*4+2] + ux * Bv.z;
            h[q*4+3] = exp2f(dl * a[q*4+3]) * h[q*4+3] + ux * Bv.w;
        }
    }
    long chbase = ((long)(b * NCHUNK + c) * D_INNER + d) * D_STATE;
    #pragma unroll
    for (int q = 0; q < 4; ++q) {
        float4 pv = {exp2f(a[q*4+0] * cum), exp2f(a[q*4+1] * cum),
                     exp2f(a[q*4+2] * cum), exp2f(a[q*4+3] * cum)};
        *(float4*)&Pout[chbase + q * 4] = pv;
        float4 hv = {h[q*4+0], h[q*4+1], h[q*4+2], h[q*4+3]};
        *(float4*)&Hout[chbase + q * 4] = hv;
    }
}

// Serial chunk-prefix scan; 8-deep register prefetch to hide load latency.
__global__ __launch_bounds__(256) void scan_chunkscan_kernel(const float* __restrict__ P,
                                                             const float* __restrict__ H,
                                                             float* __restrict__ hinit)
{
    long i = (long)blockIdx.x * 256 + threadIdx.x;  // over BATCH*D_INNER*D_STATE
    int n = (int)(i & (D_STATE - 1));
    int d = (int)((i >> 4) & (D_INNER - 1));
    int b = (int)(i >> 15);
    const long cstride = (long)D_INNER * D_STATE;
    long base = ((long)b * NCHUNK) * cstride + (long)d * D_STATE + n;
    float h = 0.f;
    for (int g = 0; g < NCHUNK / 8; ++g) {
        float Pr[8], Hr[8];
        #pragma unroll
        for (int j = 0; j < 8; ++j) {
            long o = base + (long)(g * 8 + j) * cstride;
            Pr[j] = P[o];
            Hr[j] = H[o];
        }
        #pragma unroll
        for (int j = 0; j < 8; ++j) {
            long o = base + (long)(g * 8 + j) * cstride;
            hinit[o] = h;
            h = Pr[j] * h + Hr[j];
        }
    }
}

__global__ __launch_bounds__(256) void scan_final_kernel(const ushort* __restrict__ deltab,
                                                         const ushort* __restrict__ xbb,
                                                         const float* __restrict__ xpj,
                                                         const ushort* __restrict__ xzb,
                                                         const float* __restrict__ A_log,
                                                         const float* __restrict__ Dp,
                                                         const float* __restrict__ hinit,
                                                         ushort* __restrict__ yb)
{
    __shared__ float bc[CHUNK][32];
    int blk = blockIdx.x;
    int db = blk & 7;
    int c  = (blk >> 3) & (NCHUNK - 1);
    int b  = blk >> (3 + LOG2_NCHUNK);
    int d  = db * 256 + threadIdx.x;
    long tok0 = (long)b * SEQLEN + c * CHUNK;
    for (int i = threadIdx.x; i < CHUNK * 32; i += 256) {
        int t = i >> 5, cc = i & 31;
        bc[t][cc] = xpj[(tok0 + t) * XPJ_N + DT_RANK + cc];
    }
    float a[16], h[16];
    #pragma unroll
    for (int q = 0; q < 4; ++q) {
        float4 al = *(const float4*)&A_log[d * D_STATE + q * 4];
        a[q*4+0] = -__expf(al.x) * LOG2E;
        a[q*4+1] = -__expf(al.y) * LOG2E;
        a[q*4+2] = -__expf(al.z) * LOG2E;
        a[q*4+3] = -__expf(al.w) * LOG2E;
    }
    long chbase = ((long)(b * NCHUNK + c) * D_INNER + d) * D_STATE;
    #pragma unroll
    for (int q = 0; q < 4; ++q) {
        float4 hv = *(const float4*)&hinit[chbase + q * 4];
        h[q*4+0] = hv.x; h[q*4+1] = hv.y; h[q*4+2] = hv.z; h[q*4+3] = hv.w;
    }
    float dpar = Dp[d];
    const ushort* dp = deltab + tok0 * D_INNER + d;
    const ushort* xp = xbb + tok0 * D_INNER + d;
    const ushort* zp = xzb + tok0 * NPROJ + D_INNER + d;
    ushort* yp = yb + tok0 * D_INNER + d;
    __syncthreads();
    for (int t = 0; t < CHUNK; ++t) {
        float dl = bf2f(dp[(long)t * D_INNER]);
        float x  = bf2f(xp[(long)t * D_INNER]);
        float z  = bf2f(zp[(long)t * NPROJ]);
        float ux = dl * x;
        float y = 0.f;
        #pragma unroll
        for (int q = 0; q < 4; ++q) {
            float4 Bv = *(const float4*)&bc[t][q * 4];
            float4 Cv = *(const float4*)&bc[t][16 + q * 4];
            h[q*4+0] = exp2f(dl * a[q*4+0]) * h[q*4+0] + ux * Bv.x;
            h[q*4+1] = exp2f(dl * a[q*4+1]) * h[q*4+1] + ux * Bv.y;
            h[q*4+2] = exp2f(dl * a[q*4+2]) * h[q*4+2] + ux * Bv.z;
            h[q*4+3] = exp2f(dl * a[q*4+3]) * h[q*4+3] + ux * Bv.w;
            y += h[q*4+0] * Cv.x + h[q*4+1] * Cv.y + h[q*4+2] * Cv.z + h[q*4+3] * Cv.w;
        }
        y += x * dpar;
        yp[(long)t * D_INNER] = f2bf_bits(y * (z * sigmoidf_(z)));
    }
}

extern "C" void kernel_launch(void* const* d_in, const int* in_sizes, int n_in,
                              void* d_out, int out_size, void* d_ws, size_t ws_size,
                              hipStream_t stream) {
    const float* x         = (const float*)d_in[0];
    const float* ln_gamma  = (const float*)d_in[1];
    const float* ln_beta   = (const float*)d_in[2];
    const float* in_proj_w = (const float*)d_in[3];
    const float* conv_w    = (const float*)d_in[4];
    const float* conv_b    = (const float*)d_in[5];
    const float* x_proj_w  = (const float*)d_in[6];
    const float* dt_proj_w = (const float*)d_in[7];
    const float* dt_proj_b = (const float*)d_in[8];
    const float* A_log     = (const float*)d_in[9];
    const float* D_param   = (const float*)d_in[10];
    const float* out_proj_w= (const float*)d_in[11];
    float* out = (float*)d_out;

    // Clean disjoint arena (d_ws ≈ 268 MB; used ≈ 135 MB).
    float* p = (float*)d_ws;
    ushort* hb      = (ushort*)p; p += 1048576;   // [2048][1024] bf16
    ushort* W2T     = (ushort*)p; p += 2097152;   // [4096][1024] bf16
    ushort* W7T     = (ushort*)p; p += 1048576;   // [1024][2048] bf16
    ushort* XPT     = (ushort*)p; p += 163840;    // [160][2048] bf16
    ushort* DTT     = (ushort*)p; p += 131072;    // [2048][128] bf16
    ushort* xz_bf16 = (ushort*)p; p += 4194304;   // [2048 tok][4096] bf16
    ushort* xb_bf16 = (ushort*)p; p += 2097152;   // [tok][2048] bf16
    float*  xpj     = p;          p += 327680;    // [tok][160] f32
    ushort* dtr     = (ushort*)p; p += 131072;    // [tok][128] bf16
    ushort* delta_bf16 = (ushort*)p; p += 2097152;// [tok][2048] bf16
    ushort* Ppart   = (ushort*)p; p += 1310720;   // gemm4 partials [8][2048][160] bf16
    float*  Pbuf    = p;          p += 4194304;   // scan P  [B][64][2048][16] f32
    float*  Hbuf    = p;          p += 4194304;   // scan H
    float*  hinit   = p;          p += 4194304;
    ushort* y_bf16  = (ushort*)p; p += 2097152;   // [tok][2048] bf16
    ushort* PpartO  = (ushort*)p; p += 4194304;   // out_proj partials [4][2048][1024] bf16

    // 0. all four weight transposes, one dispatch
    transpose_all_kernel<<<1696, 256, 0, stream>>>(
        in_proj_w, W2T, out_proj_w, W7T, x_proj_w, XPT, dt_proj_w, DTT);

    // 1. LayerNorm → bf16
    ln_kernel<<<NTOK, 256, 0, stream>>>(x, ln_gamma, ln_beta, hb);

    // 2. xz = h @ in_proj_w (MFMA 2-phase, bf16 out, XCD swizzle)
    gemm_mfma_kernel<0, 1><<<dim3(NPROJ / 128, NTOK / 128), 256, 0, stream>>>(
        hb, W2T, nullptr, nullptr, xz_bf16, NTOK, NPROJ, D_MODEL, D_MODEL, D_MODEL);

    // 3. conv4 + bias + SiLU (bf16 in/out)
    conv_silu_kernel<<<(NTOK * D_INNER) / 256, 256, 0, stream>>>(
        xz_bf16, conv_w, conv_b, xb_bf16);

    // 4. xpj partials (split-K MFMA, bf16) then reduce → xpj f32 + dtr bf16
    gemm4_mfma_kernel<<<dim3(SPLITK, NTOK / 64), 256, 0, stream>>>(
        xb_bf16, XPT, Ppart, NTOK, D_INNER);
    reduce_xpj_kernel<<<(NTOK * XPJ_N) / 256, 256, 0, stream>>>(Ppart, xpj, dtr);

    // 5. delta = softplus(dt_r @ dt_proj_w + b) (MFMA 128x64 2-phase, bf16 out)
    gemm_mfma64_kernel<1, 1><<<dim3(D_INNER / 64, NTOK / 128), 256, 0, stream>>>(
        dtr, DTT, dt_proj_b, nullptr, delta_bf16, NTOK, D_INNER, DT_RANK);

    // 6. chunked selective scan (1 lane/channel, CHUNK=16, LDS-staged B/C)
    scan_partial_kernel<<<BATCH * NCHUNK * 8, 256, 0, stream>>>(
        delta_bf16, xb_bf16, xpj, A_log, Pbuf, Hbuf);
    scan_chunkscan_kernel<<<(BATCH * D_INNER * D_STATE) / 256, 256, 0, stream>>>(
        Pbuf, Hbuf, hinit);
    scan_final_kernel<<<BATCH * NCHUNK * 8, 256, 0, stream>>>(
        delta_bf16, xb_bf16, xpj, xz_bf16, A_log, D_param, hinit, y_bf16);

    // 7. out_proj split-K=4: 2-phase partials (bf16) then fused reduce+residual
    gemm_mfma_kernel<0, 1><<<dim3(D_MODEL / 128, NTOK / 128, OP_SPLITK), 256, 0, stream>>>(
        y_bf16, W7T, nullptr, nullptr, PpartO, NTOK, D_MODEL, D_INNER / OP_SPLITK,
        D_INNER, D_INNER);
    reduce_out_kernel<<<(NTOK * D_MODEL / 4) / 256, 256, 0, stream>>>(PpartO, x, out);
}

// Round 17
// 173.175 us; speedup vs baseline: 1.2044x; 1.0616x over previous
//
#include <hip/hip_runtime.h>
#include <hip/hip_bf16.h>

#define D_MODEL 1024
#define D_INNER 2048
#define NPROJ   4096   /* 2*D_INNER */
#define D_STATE 16
#define DT_RANK 128
#define XPJ_N   160    /* DT_RANK + 2*D_STATE */
#define SEQLEN  1024
#define BATCH   2
#define NTOK    2048   /* BATCH*SEQLEN */
#define CHUNK   16
#define NCHUNK  (SEQLEN / CHUNK)   /* 64 */
#define LOG2_NCHUNK 6
#define SPLITK  8      /* gemm4 split */
#define OP_SPLITK 4    /* out_proj split */

typedef short short8 __attribute__((ext_vector_type(8)));
typedef unsigned short ushort8v __attribute__((ext_vector_type(8)));
typedef float f32x4 __attribute__((ext_vector_type(4)));

__device__ __forceinline__ float sigmoidf_(float x) { return 1.f / (1.f + __expf(-x)); }
__device__ __forceinline__ ushort f2bf_bits(float f) {
    __hip_bfloat16 h = __float2bfloat16(f);
    return *(ushort*)&h;
}
__device__ __forceinline__ float bf2f(ushort u) {
    union { unsigned int i; float f; } v;
    v.i = ((unsigned int)u) << 16;
    return v.f;
}
#define LOG2E 1.44269504088896f

// ---------------- LayerNorm → bf16 output ----------------
__global__ __launch_bounds__(256) void ln_kernel(const float* __restrict__ x,
                                                 const float* __restrict__ g,
                                                 const float* __restrict__ be,
                                                 ushort* __restrict__ hb)
{
    int row = blockIdx.x;
    const float4* xr = (const float4*)(x + (long)row * D_MODEL);
    float4 v = xr[threadIdx.x];
    float s1 = v.x + v.y + v.z + v.w;
    float s2 = v.x*v.x + v.y*v.y + v.z*v.z + v.w*v.w;
    for (int off = 32; off >= 1; off >>= 1) {
        s1 += __shfl_down(s1, off);
        s2 += __shfl_down(s2, off);
    }
    __shared__ float red[8];
    int wid = threadIdx.x >> 6;
    if ((threadIdx.x & 63) == 0) { red[wid] = s1; red[4 + wid] = s2; }
    __syncthreads();
    float mu  = (red[0] + red[1] + red[2] + red[3]) * (1.f / D_MODEL);
    float ex2 = (red[4] + red[5] + red[6] + red[7]) * (1.f / D_MODEL);
    float inv = rsqrtf(ex2 - mu * mu + 1e-5f);
    float4 g4 = ((const float4*)g)[threadIdx.x];
    float4 b4 = ((const float4*)be)[threadIdx.x];
    ushort4 o;
    o.x = f2bf_bits((v.x - mu) * inv * g4.x + b4.x);
    o.y = f2bf_bits((v.y - mu) * inv * g4.y + b4.y);
    o.z = f2bf_bits((v.z - mu) * inv * g4.z + b4.z);
    o.w = f2bf_bits((v.w - mu) * inv * g4.w + b4.w);
    *(ushort4*)(hb + (long)row * D_MODEL + threadIdx.x * 4) = o;
}

// ---------------- batched f32 [R][C] → bf16 [C][R] transpose (4 weights, 1 dispatch) --
__device__ __forceinline__ void transpose_tile(const float* __restrict__ in,
                                               ushort* __restrict__ out,
                                               int R, int C, int cx, int ry)
{
    __shared__ float tile[64][65];
    int c0 = cx * 64, r0 = ry * 64;
    #pragma unroll
    for (int i = 0; i < 16; ++i) {
        int idx = threadIdx.x + i * 256;
        int r = idx >> 6, c = idx & 63;
        tile[r][c] = (r0 + r < R && c0 + c < C) ? in[(long)(r0 + r) * C + (c0 + c)] : 0.f;
    }
    __syncthreads();
    #pragma unroll
    for (int i = 0; i < 16; ++i) {
        int idx = threadIdx.x + i * 256;
        int cc = idx >> 6, rr = idx & 63;
        if (c0 + cc < C && r0 + rr < R)
            out[(long)(c0 + cc) * R + (r0 + rr)] = f2bf_bits(tile[rr][cc]);
    }
}

__global__ __launch_bounds__(256) void transpose_all_kernel(const float* __restrict__ w2,
                                                            ushort* __restrict__ W2T,
                                                            const float* __restrict__ w7,
                                                            ushort* __restrict__ W7T,
                                                            const float* __restrict__ xp,
                                                            ushort* __restrict__ XPT,
                                                            const float* __restrict__ dt,
                                                            ushort* __restrict__ DTT)
{
    int idx = blockIdx.x;
    if (idx < 1024) {
        transpose_tile(w2, W2T, D_MODEL, NPROJ, idx & 63, idx >> 6);
    } else if (idx < 1536) {
        int rel = idx - 1024;
        transpose_tile(w7, W7T, D_INNER, D_MODEL, rel & 15, rel >> 4);
    } else if (idx < 1632) {
        int rel = idx - 1536;
        transpose_tile(xp, XPT, D_INNER, XPJ_N, rel % 3, rel / 3);
    } else {
        int rel = idx - 1632;
        transpose_tile(dt, DTT, DT_RANK, D_INNER, rel & 31, rel >> 5);
    }
}

// ---------------- bf16 MFMA GEMM 128x128, 2-phase double-buffered pipeline -----------
template <int EPI, int OBF>
__global__ __launch_bounds__(256) void gemm_mfma_kernel(const ushort* __restrict__ A,
                                                        const ushort* __restrict__ Bt,
                                                        const float* __restrict__ bias,
                                                        float* __restrict__ Cf,
                                                        ushort* __restrict__ Cb,
                                                        int M, int N, int K, int lda, int ldb)
{
    long zoff = (long)blockIdx.z;
    A  += zoff * K;
    Bt += zoff * K;
    if (OBF == 0) Cf += zoff * (long)M * N;
    else          Cb += zoff * (long)M * N;
    int lin = blockIdx.y * gridDim.x + blockIdx.x;
    int cpx = (gridDim.x * gridDim.y) >> 3;
    lin = (lin & 7) * cpx + (lin >> 3);
    int bx = lin % gridDim.x, by = lin / gridDim.x;
    __shared__ __align__(16) ushort Al[2][128 * 32];
    __shared__ __align__(16) ushort Bl[2][128 * 32];
    int tid = threadIdx.x;
    int lane = tid & 63;
    int w = tid >> 6, wr = w >> 1, wc = w & 1;
    int m0 = by * 128, n0 = bx * 128;
    f32x4 acc[4][4];
    #pragma unroll
    for (int m = 0; m < 4; ++m)
        #pragma unroll
        for (int n = 0; n < 4; ++n) acc[m][n] = (f32x4){0.f, 0.f, 0.f, 0.f};
    int l15 = lane & 15, kq = lane >> 4;

    auto stage = [&](int buf, int k0) {
        #pragma unroll
        for (int i = 0; i < 2; ++i) {
            int s = i * 256 + tid;
            int row = s >> 2, kg = s & 3;
            int kgl = kg ^ ((row >> 1) & 3);
            __builtin_amdgcn_global_load_lds(
                (const __attribute__((address_space(1))) void*)(A + (long)(m0 + row) * lda + k0 + kgl * 8),
                (__attribute__((address_space(3))) void*)(Al[buf] + s * 8), 16, 0, 0);
            __builtin_amdgcn_global_load_lds(
                (const __attribute__((address_space(1))) void*)(Bt + (long)(n0 + row) * ldb + k0 + kgl * 8),
                (__attribute__((address_space(3))) void*)(Bl[buf] + s * 8), 16, 0, 0);
        }
    };

    stage(0, 0);
    int cur = 0;
    for (int k0 = 0; k0 < K; k0 += 32) {
        if (k0 + 32 < K) {
            stage(cur ^ 1, k0 + 32);
            asm volatile("s_waitcnt vmcnt(4)" ::: "memory");
        } else {
            asm volatile("s_waitcnt vmcnt(0)" ::: "memory");
        }
        __builtin_amdgcn_s_barrier();
        asm volatile("" ::: "memory");
        short8 af[4], bf[4];
        #pragma unroll
        for (int m = 0; m < 4; ++m) {
            int row = wr * 64 + m * 16 + l15;
            af[m] = *(const short8*)&Al[cur][row * 32 + (kq ^ ((row >> 1) & 3)) * 8];
        }
        #pragma unroll
        for (int n = 0; n < 4; ++n) {
            int row = wc * 64 + n * 16 + l15;
            bf[n] = *(const short8*)&Bl[cur][row * 32 + (kq ^ ((row >> 1) & 3)) * 8];
        }
        #pragma unroll
        for (int m = 0; m < 4; ++m)
            #pragma unroll
            for (int n = 0; n < 4; ++n)
                acc[m][n] = __builtin_amdgcn_mfma_f32_16x16x32_bf16(af[m], bf[n], acc[m][n], 0, 0, 0);
        asm volatile("" ::: "memory");
        __builtin_amdgcn_s_barrier();
        asm volatile("" ::: "memory");
        cur ^= 1;
    }
    #pragma unroll
    for (int m = 0; m < 4; ++m) {
        #pragma unroll
        for (int n = 0; n < 4; ++n) {
            #pragma unroll
            for (int r = 0; r < 4; ++r) {
                int row = m0 + wr * 64 + m * 16 + kq * 4 + r;
                int col = n0 + wc * 64 + n * 16 + l15;
                float v = acc[m][n][r];
                if (EPI == 1) {
                    v += bias[col];
                    v = (v > 20.f) ? v : log1pf(__expf(v));
                }
                if (OBF) Cb[(long)row * N + col] = f2bf_bits(v);
                else     Cf[(long)row * N + col] = v;
            }
        }
    }
}

// ---------------- bf16 MFMA GEMM 128x64, 2-phase double-buffered (vmcnt(3)) ----------
template <int EPI, int OBF>
__global__ __launch_bounds__(256) void gemm_mfma64_kernel(const ushort* __restrict__ A,
                                                          const ushort* __restrict__ Bt,
                                                          const float* __restrict__ bias,
                                                          float* __restrict__ Cf,
                                                          ushort* __restrict__ Cb,
                                                          int M, int N, int K)
{
    int lin = blockIdx.y * gridDim.x + blockIdx.x;
    int cpx = (gridDim.x * gridDim.y) >> 3;
    lin = (lin & 7) * cpx + (lin >> 3);
    int bx = lin % gridDim.x, by = lin / gridDim.x;
    __shared__ __align__(16) ushort Al[2][128 * 32];
    __shared__ __align__(16) ushort Bl[2][64 * 32];
    int tid = threadIdx.x;
    int lane = tid & 63;
    int w = tid >> 6, wr = w >> 1, wc = w & 1;
    int m0 = by * 128, n0 = bx * 64;
    f32x4 acc[4][2];
    #pragma unroll
    for (int m = 0; m < 4; ++m)
        #pragma unroll
        for (int n = 0; n < 2; ++n) acc[m][n] = (f32x4){0.f, 0.f, 0.f, 0.f};
    int l15 = lane & 15, kq = lane >> 4;

    auto stage = [&](int buf, int k0) {
        #pragma unroll
        for (int i = 0; i < 2; ++i) {
            int s = i * 256 + tid;
            int row = s >> 2, kg = s & 3;
            int kgl = kg ^ ((row >> 1) & 3);
            __builtin_amdgcn_global_load_lds(
                (const __attribute__((address_space(1))) void*)(A + (long)(m0 + row) * K + k0 + kgl * 8),
                (__attribute__((address_space(3))) void*)(Al[buf] + s * 8), 16, 0, 0);
        }
        {
            int s = tid;
            int row = s >> 2, kg = s & 3;
            int kgl = kg ^ ((row >> 1) & 3);
            __builtin_amdgcn_global_load_lds(
                (const __attribute__((address_space(1))) void*)(Bt + (long)(n0 + row) * K + k0 + kgl * 8),
                (__attribute__((address_space(3))) void*)(Bl[buf] + s * 8), 16, 0, 0);
        }
    };

    stage(0, 0);
    int cur = 0;
    for (int k0 = 0; k0 < K; k0 += 32) {
        if (k0 + 32 < K) {
            stage(cur ^ 1, k0 + 32);
            asm volatile("s_waitcnt vmcnt(3)" ::: "memory");
        } else {
            asm volatile("s_waitcnt vmcnt(0)" ::: "memory");
        }
        __builtin_amdgcn_s_barrier();
        asm volatile("" ::: "memory");
        short8 af[4], bf[2];
        #pragma unroll
        for (int m = 0; m < 4; ++m) {
            int row = wr * 64 + m * 16 + l15;
            af[m] = *(const short8*)&Al[cur][row * 32 + (kq ^ ((row >> 1) & 3)) * 8];
        }
        #pragma unroll
        for (int n = 0; n < 2; ++n) {
            int row = wc * 32 + n * 16 + l15;
            bf[n] = *(const short8*)&Bl[cur][row * 32 + (kq ^ ((row >> 1) & 3)) * 8];
        }
        #pragma unroll
        for (int m = 0; m < 4; ++m)
            #pragma unroll
            for (int n = 0; n < 2; ++n)
                acc[m][n] = __builtin_amdgcn_mfma_f32_16x16x32_bf16(af[m], bf[n], acc[m][n], 0, 0, 0);
        asm volatile("" ::: "memory");
        __builtin_amdgcn_s_barrier();
        asm volatile("" ::: "memory");
        cur ^= 1;
    }
    #pragma unroll
    for (int m = 0; m < 4; ++m) {
        #pragma unroll
        for (int n = 0; n < 2; ++n) {
            #pragma unroll
            for (int r = 0; r < 4; ++r) {
                int row = m0 + wr * 64 + m * 16 + kq * 4 + r;
                int col = n0 + wc * 32 + n * 16 + l15;
                float v = acc[m][n][r];
                if (EPI == 1) {
                    v += bias[col];
                    v = (v > 20.f) ? v : log1pf(__expf(v));
                }
                if (OBF) Cb[(long)row * N + col] = f2bf_bits(v);
                else     Cf[(long)row * N + col] = v;
            }
        }
    }
}

// -------- out_proj split-K reduce (bf16 partials): out = sum_k Ppart[k] + resid ------
__global__ __launch_bounds__(256) void reduce_out_kernel(const ushort* __restrict__ Ppart,
                                                         const float* __restrict__ resid,
                                                         float* __restrict__ out)
{
    long i = (long)blockIdx.x * 256 + threadIdx.x;   // over NTOK*D_MODEL/4
    const long STRIDE = (long)NTOK * D_MODEL;
    float4 s;
    ushort4 p0 = ((const ushort4*)Ppart)[i];
    s.x = bf2f(p0.x); s.y = bf2f(p0.y); s.z = bf2f(p0.z); s.w = bf2f(p0.w);
    #pragma unroll
    for (int k = 1; k < OP_SPLITK; ++k) {
        ushort4 pk = ((const ushort4*)(Ppart + k * STRIDE))[i];
        s.x += bf2f(pk.x); s.y += bf2f(pk.y); s.z += bf2f(pk.z); s.w += bf2f(pk.w);
    }
    float4 r = ((const float4*)resid)[i];
    s.x += r.x; s.y += r.y; s.z += r.z; s.w += r.w;
    ((float4*)out)[i] = s;
}

// -------- split-K bf16 MFMA GEMM for xpj (bf16 partials out) --------
__global__ __launch_bounds__(256) void gemm4_mfma_kernel(const ushort* __restrict__ A,
                                                         const ushort* __restrict__ Bt,
                                                         ushort* __restrict__ Ppart,
                                                         int M, int K)
{
    __shared__ __align__(16) ushort Al[64 * 32];
    __shared__ __align__(16) ushort Bl[160 * 32];
    int tid = threadIdx.x;
    int lane = tid & 63;
    int w = tid >> 6, wr = w >> 1, wc = w & 1;
    int sk = blockIdx.x;
    int m0 = blockIdx.y * 64;
    int kbase = sk * (K / SPLITK);
    f32x4 acc[2][5];
    #pragma unroll
    for (int m = 0; m < 2; ++m)
        #pragma unroll
        for (int n = 0; n < 5; ++n) acc[m][n] = (f32x4){0.f, 0.f, 0.f, 0.f};
    int l15 = lane & 15, kq = lane >> 4;

    for (int ks = 0; ks < K / SPLITK; ks += 32) {
        int k0 = kbase + ks;
        {
            int s = tid;
            int row = s >> 2, kg = s & 3;
            int kgl = kg ^ ((row >> 1) & 3);
            __builtin_amdgcn_global_load_lds(
                (const __attribute__((address_space(1))) void*)(A + (long)(m0 + row) * K + k0 + kgl * 8),
                (__attribute__((address_space(3))) void*)(Al + s * 8), 16, 0, 0);
        }
        #pragma unroll
        for (int i = 0; i < 3; ++i) {
            int s = i * 256 + tid;
            if (s < 640) {
                int row = s >> 2, kg = s & 3;
                int kgl = kg ^ ((row >> 1) & 3);
                __builtin_amdgcn_global_load_lds(
                    (const __attribute__((address_space(1))) void*)(Bt + (long)row * K + k0 + kgl * 8),
                    (__attribute__((address_space(3))) void*)(Bl + s * 8), 16, 0, 0);
            }
        }
        __syncthreads();
        short8 af[2], bf[5];
        #pragma unroll
        for (int m = 0; m < 2; ++m) {
            int row = wr * 32 + m * 16 + l15;
            af[m] = *(const short8*)&Al[row * 32 + (kq ^ ((row >> 1) & 3)) * 8];
        }
        #pragma unroll
        for (int n = 0; n < 5; ++n) {
            int row = wc * 80 + n * 16 + l15;
            bf[n] = *(const short8*)&Bl[row * 32 + (kq ^ ((row >> 1) & 3)) * 8];
        }
        #pragma unroll
        for (int m = 0; m < 2; ++m)
            #pragma unroll
            for (int n = 0; n < 5; ++n)
                acc[m][n] = __builtin_amdgcn_mfma_f32_16x16x32_bf16(af[m], bf[n], acc[m][n], 0, 0, 0);
        __syncthreads();
    }
    ushort* P = Ppart + (long)sk * M * XPJ_N;
    #pragma unroll
    for (int m = 0; m < 2; ++m) {
        #pragma unroll
        for (int n = 0; n < 5; ++n) {
            #pragma unroll
            for (int r = 0; r < 4; ++r) {
                int row = m0 + wr * 32 + m * 16 + kq * 4 + r;
                int col = wc * 80 + n * 16 + l15;
                P[(long)row * XPJ_N + col] = f2bf_bits(acc[m][n][r]);
            }
        }
    }
}

// -------- reduce split-K bf16 partials → xpj f32 + dt_r bf16 --------
__global__ __launch_bounds__(256) void reduce_xpj_kernel(const ushort* __restrict__ Ppart,
                                                         float* __restrict__ xpj,
                                                         ushort* __restrict__ dtr)
{
    long i = (long)blockIdx.x * 256 + threadIdx.x;   // over NTOK*XPJ_N
    float s = 0.f;
    #pragma unroll
    for (int k = 0; k < SPLITK; ++k) s += bf2f(Ppart[k * (long)NTOK * XPJ_N + i]);
    xpj[i] = s;
    int col = (int)(i % XPJ_N);
    long row = i / XPJ_N;
    if (col < DT_RANK) dtr[row * DT_RANK + col] = f2bf_bits(s);
}

// ---------------- depthwise causal conv (width 4) + bias + SiLU; vectorized ushort8 ---
// Each thread: 8 consecutive d of one token. Grid over NTOK*D_INNER/8 / 256.
__global__ __launch_bounds__(256) void conv_silu_kernel(const ushort* __restrict__ xzb,
                                                        const float* __restrict__ cw,
                                                        const float* __restrict__ cb,
                                                        ushort* __restrict__ xbb)
{
    long i = (long)blockIdx.x * 256 + threadIdx.x;   // over NTOK*(D_INNER/8)
    int d8 = (int)(i & (D_INNER / 8 - 1));
    long tok = i >> 8;
    int l = (int)(tok & (SEQLEN - 1));
    int d0 = d8 * 8;
    const ushort* base = xzb + tok * NPROJ + d0;
    ushort8v r3 = *(const ushort8v*)base;
    ushort8v r2 = {0,0,0,0,0,0,0,0}, r1 = r2, r0 = r2;
    if (l >= 1) r2 = *(const ushort8v*)(base - NPROJ);
    if (l >= 2) r1 = *(const ushort8v*)(base - 2 * NPROJ);
    if (l >= 3) r0 = *(const ushort8v*)(base - 3 * NPROJ);
    ushort8v o;
    #pragma unroll
    for (int j = 0; j < 8; ++j) {
        int d = d0 + j;
        float4 wv = *(const float4*)&cw[d * 4];
        float acc = cb[d]
                  + bf2f(r0[j]) * wv.x + bf2f(r1[j]) * wv.y
                  + bf2f(r2[j]) * wv.z + bf2f(r3[j]) * wv.w;
        o[j] = f2bf_bits(acc * sigmoidf_(acc));
    }
    *(ushort8v*)(xbb + tok * D_INNER + d0) = o;
}

// ======================= chunked selective scan: 1 lane/channel, CHUNK=16 =============
__global__ __launch_bounds__(256) void scan_partial_kernel(const ushort* __restrict__ deltab,
                                                           const ushort* __restrict__ xbb,
                                                           const float* __restrict__ xpj,
                                                           const float* __restrict__ A_log,
                                                           float* __restrict__ Pout,
                                                           float* __restrict__ Hout)
{
    __shared__ float bc[CHUNK][32];
    int blk = blockIdx.x;
    int db = blk & 7;
    int c  = (blk >> 3) & (NCHUNK - 1);
    int b  = blk >> (3 + LOG2_NCHUNK);
    int d  = db * 256 + threadIdx.x;
    long tok0 = (long)b * SEQLEN + c * CHUNK;
    for (int i = threadIdx.x; i < CHUNK * 32; i += 256) {
        int t = i >> 5, cc = i & 31;
        bc[t][cc] = xpj[(tok0 + t) * XPJ_N + DT_RANK + cc];
    }
    float a[16], h[16];
    #pragma unroll
    for (int q = 0; q < 4; ++q) {
        float4 al = *(const float4*)&A_log[d * D_STATE + q * 4];
        a[q*4+0] = -__expf(al.x) * LOG2E;
        a[q*4+1] = -__expf(al.y) * LOG2E;
        a[q*4+2] = -__expf(al.z) * LOG2E;
        a[q*4+3] = -__expf(al.w) * LOG2E;
    }
    #pragma unroll
    for (int n = 0; n < 16; ++n) h[n] = 0.f;
    float cum = 0.f;
    const ushort* dp = deltab + tok0 * D_INNER + d;
    const ushort* xp = xbb + tok0 * D_INNER + d;
    __syncthreads();
    #pragma unroll
    for (int t = 0; t < CHUNK; ++t) {
        float dl = bf2f(dp[(long)t * D_INNER]);
        float x  = bf2f(xp[(long)t * D_INNER]);
        float ux = dl * x;
        cum += dl;
        #pragma unroll
        for (int q = 0; q < 4; ++q) {
            float4 Bv = *(const float4*)&bc[t][q * 4];
            h[q*4+0] = exp2f(dl * a[q*4+0]) * h[q*4+0] + ux * Bv.x;
            h[q*4+1] = exp2f(dl * a[q*4+1]) * h[q*4+1] + ux * Bv.y;
            h[q*4+2] = exp2f(dl * a[q*4+2]) * h[q*4+2] + ux * Bv.z;
            h[q*4+3] = exp2f(dl * a[q*4+3]) * h[q*4+3] + ux * Bv.w;
        }
    }
    long chbase = ((long)(b * NCHUNK + c) * D_INNER + d) * D_STATE;
    #pragma unroll
    for (int q = 0; q < 4; ++q) {
        float4 pv = {exp2f(a[q*4+0] * cum), exp2f(a[q*4+1] * cum),
                     exp2f(a[q*4+2] * cum), exp2f(a[q*4+3] * cum)};
        *(float4*)&Pout[chbase + q * 4] = pv;
        float4 hv = {h[q*4+0], h[q*4+1], h[q*4+2], h[q*4+3]};
        *(float4*)&Hout[chbase + q * 4] = hv;
    }
}

// Serial chunk-prefix scan; 8-deep register prefetch; bf16 hinit out.
__global__ __launch_bounds__(256) void scan_chunkscan_kernel(const float* __restrict__ P,
                                                             const float* __restrict__ H,
                                                             ushort* __restrict__ hinit)
{
    long i = (long)blockIdx.x * 256 + threadIdx.x;  // over BATCH*D_INNER*D_STATE
    int n = (int)(i & (D_STATE - 1));
    int d = (int)((i >> 4) & (D_INNER - 1));
    int b = (int)(i >> 15);
    const long cstride = (long)D_INNER * D_STATE;
    long base = ((long)b * NCHUNK) * cstride + (long)d * D_STATE + n;
    float h = 0.f;
    for (int g = 0; g < NCHUNK / 8; ++g) {
        float Pr[8], Hr[8];
        #pragma unroll
        for (int j = 0; j < 8; ++j) {
            long o = base + (long)(g * 8 + j) * cstride;
            Pr[j] = P[o];
            Hr[j] = H[o];
        }
        #pragma unroll
        for (int j = 0; j < 8; ++j) {
            long o = base + (long)(g * 8 + j) * cstride;
            hinit[o] = f2bf_bits(h);
            h = Pr[j] * h + Hr[j];
        }
    }
}

__global__ __launch_bounds__(256) void scan_final_kernel(const ushort* __restrict__ deltab,
                                                         const ushort* __restrict__ xbb,
                                                         const float* __restrict__ xpj,
                                                         const ushort* __restrict__ xzb,
                                                         const float* __restrict__ A_log,
                                                         const float* __restrict__ Dp,
                                                         const ushort* __restrict__ hinit,
                                                         ushort* __restrict__ yb)
{
    __shared__ float bc[CHUNK][32];
    int blk = blockIdx.x;
    int db = blk & 7;
    int c  = (blk >> 3) & (NCHUNK - 1);
    int b  = blk >> (3 + LOG2_NCHUNK);
    int d  = db * 256 + threadIdx.x;
    long tok0 = (long)b * SEQLEN + c * CHUNK;
    for (int i = threadIdx.x; i < CHUNK * 32; i += 256) {
        int t = i >> 5, cc = i & 31;
        bc[t][cc] = xpj[(tok0 + t) * XPJ_N + DT_RANK + cc];
    }
    float a[16], h[16];
    #pragma unroll
    for (int q = 0; q < 4; ++q) {
        float4 al = *(const float4*)&A_log[d * D_STATE + q * 4];
        a[q*4+0] = -__expf(al.x) * LOG2E;
        a[q*4+1] = -__expf(al.y) * LOG2E;
        a[q*4+2] = -__expf(al.z) * LOG2E;
        a[q*4+3] = -__expf(al.w) * LOG2E;
    }
    long chbase = ((long)(b * NCHUNK + c) * D_INNER + d) * D_STATE;
    #pragma unroll
    for (int q = 0; q < 4; ++q) {
        ushort4 hv = *(const ushort4*)&hinit[chbase + q * 4];
        h[q*4+0] = bf2f(hv.x); h[q*4+1] = bf2f(hv.y);
        h[q*4+2] = bf2f(hv.z); h[q*4+3] = bf2f(hv.w);
    }
    float dpar = Dp[d];
    const ushort* dp = deltab + tok0 * D_INNER + d;
    const ushort* xp = xbb + tok0 * D_INNER + d;
    const ushort* zp = xzb + tok0 * NPROJ + D_INNER + d;
    ushort* yp = yb + tok0 * D_INNER + d;
    __syncthreads();
    #pragma unroll
    for (int t = 0; t < CHUNK; ++t) {
        float dl = bf2f(dp[(long)t * D_INNER]);
        float x  = bf2f(xp[(long)t * D_INNER]);
        float z  = bf2f(zp[(long)t * NPROJ]);
        float ux = dl * x;
        float y = 0.f;
        #pragma unroll
        for (int q = 0; q < 4; ++q) {
            float4 Bv = *(const float4*)&bc[t][q * 4];
            float4 Cv = *(const float4*)&bc[t][16 + q * 4];
            h[q*4+0] = exp2f(dl * a[q*4+0]) * h[q*4+0] + ux * Bv.x;
            h[q*4+1] = exp2f(dl * a[q*4+1]) * h[q*4+1] + ux * Bv.y;
            h[q*4+2] = exp2f(dl * a[q*4+2]) * h[q*4+2] + ux * Bv.z;
            h[q*4+3] = exp2f(dl * a[q*4+3]) * h[q*4+3] + ux * Bv.w;
            y += h[q*4+0] * Cv.x + h[q*4+1] * Cv.y + h[q*4+2] * Cv.z + h[q*4+3] * Cv.w;
        }
        y += x * dpar;
        yp[(long)t * D_INNER] = f2bf_bits(y * (z * sigmoidf_(z)));
    }
}

extern "C" void kernel_launch(void* const* d_in, const int* in_sizes, int n_in,
                              void* d_out, int out_size, void* d_ws, size_t ws_size,
                              hipStream_t stream) {
    const float* x         = (const float*)d_in[0];
    const float* ln_gamma  = (const float*)d_in[1];
    const float* ln_beta   = (const float*)d_in[2];
    const float* in_proj_w = (const float*)d_in[3];
    const float* conv_w    = (const float*)d_in[4];
    const float* conv_b    = (const float*)d_in[5];
    const float* x_proj_w  = (const float*)d_in[6];
    const float* dt_proj_w = (const float*)d_in[7];
    const float* dt_proj_b = (const float*)d_in[8];
    const float* A_log     = (const float*)d_in[9];
    const float* D_param   = (const float*)d_in[10];
    const float* out_proj_w= (const float*)d_in[11];
    float* out = (float*)d_out;

    // Clean disjoint arena (d_ws ≈ 268 MB; used ≈ 129 MB).
    float* p = (float*)d_ws;
    ushort* hb      = (ushort*)p; p += 1048576;   // [2048][1024] bf16
    ushort* W2T     = (ushort*)p; p += 2097152;   // [4096][1024] bf16
    ushort* W7T     = (ushort*)p; p += 1048576;   // [1024][2048] bf16
    ushort* XPT     = (ushort*)p; p += 163840;    // [160][2048] bf16
    ushort* DTT     = (ushort*)p; p += 131072;    // [2048][128] bf16
    ushort* xz_bf16 = (ushort*)p; p += 4194304;   // [2048 tok][4096] bf16
    ushort* xb_bf16 = (ushort*)p; p += 2097152;   // [tok][2048] bf16
    float*  xpj     = p;          p += 327680;    // [tok][160] f32
    ushort* dtr     = (ushort*)p; p += 131072;    // [tok][128] bf16
    ushort* delta_bf16 = (ushort*)p; p += 2097152;// [tok][2048] bf16
    ushort* Ppart   = (ushort*)p; p += 1310720;   // gemm4 partials [8][2048][160] bf16
    float*  Pbuf    = p;          p += 4194304;   // scan P  [B][64][2048][16] f32
    float*  Hbuf    = p;          p += 4194304;   // scan H
    ushort* hinit   = (ushort*)p; p += 2097152;   // [B][64][2048][16] bf16
    ushort* y_bf16  = (ushort*)p; p += 2097152;   // [tok][2048] bf16
    ushort* PpartO  = (ushort*)p; p += 4194304;   // out_proj partials [4][2048][1024] bf16

    // 0. all four weight transposes, one dispatch
    transpose_all_kernel<<<1696, 256, 0, stream>>>(
        in_proj_w, W2T, out_proj_w, W7T, x_proj_w, XPT, dt_proj_w, DTT);

    // 1. LayerNorm → bf16
    ln_kernel<<<NTOK, 256, 0, stream>>>(x, ln_gamma, ln_beta, hb);

    // 2. xz = h @ in_proj_w (MFMA 2-phase, bf16 out, XCD swizzle)
    gemm_mfma_kernel<0, 1><<<dim3(NPROJ / 128, NTOK / 128), 256, 0, stream>>>(
        hb, W2T, nullptr, nullptr, xz_bf16, NTOK, NPROJ, D_MODEL, D_MODEL, D_MODEL);

    // 3. conv4 + bias + SiLU (vectorized ushort8)
    conv_silu_kernel<<<(NTOK * D_INNER / 8) / 256, 256, 0, stream>>>(
        xz_bf16, conv_w, conv_b, xb_bf16);

    // 4. xpj partials (split-K MFMA, bf16) then reduce → xpj f32 + dtr bf16
    gemm4_mfma_kernel<<<dim3(SPLITK, NTOK / 64), 256, 0, stream>>>(
        xb_bf16, XPT, Ppart, NTOK, D_INNER);
    reduce_xpj_kernel<<<(NTOK * XPJ_N) / 256, 256, 0, stream>>>(Ppart, xpj, dtr);

    // 5. delta = softplus(dt_r @ dt_proj_w + b) (MFMA 128x64 2-phase, bf16 out)
    gemm_mfma64_kernel<1, 1><<<dim3(D_INNER / 64, NTOK / 128), 256, 0, stream>>>(
        dtr, DTT, dt_proj_b, nullptr, delta_bf16, NTOK, D_INNER, DT_RANK);

    // 6. chunked selective scan (1 lane/channel, CHUNK=16, LDS B/C, unrolled)
    scan_partial_kernel<<<BATCH * NCHUNK * 8, 256, 0, stream>>>(
        delta_bf16, xb_bf16, xpj, A_log, Pbuf, Hbuf);
    scan_chunkscan_kernel<<<(BATCH * D_INNER * D_STATE) / 256, 256, 0, stream>>>(
        Pbuf, Hbuf, hinit);
    scan_final_kernel<<<BATCH * NCHUNK * 8, 256, 0, stream>>>(
        delta_bf16, xb_bf16, xpj, xz_bf16, A_log, D_param, hinit, y_bf16);

    // 7. out_proj split-K=4: 2-phase partials (bf16) then fused reduce+residual
    gemm_mfma_kernel<0, 1><<<dim3(D_MODEL / 128, NTOK / 128, OP_SPLITK), 256, 0, stream>>>(
        y_bf16, W7T, nullptr, nullptr, PpartO, NTOK, D_MODEL, D_INNER / OP_SPLITK,
        D_INNER, D_INNER);
    reduce_out_kernel<<<(NTOK * D_MODEL / 4) / 256, 256, 0, stream>>>(PpartO, x, out);
}

// Round 18
// 166.282 us; speedup vs baseline: 1.2544x; 1.0415x over previous
//
#include <hip/hip_runtime.h>
#include <hip/hip_bf16.h>

#define D_MODEL 1024
#define D_INNER 2048
#define NPROJ   4096   /* 2*D_INNER */
#define D_STATE 16
#define DT_RANK 128
#define XPJ_N   160    /* DT_RANK + 2*D_STATE */
#define SEQLEN  1024
#define BATCH   2
#define NTOK    2048   /* BATCH*SEQLEN */
#define CHUNK   16
#define NCHUNK  (SEQLEN / CHUNK)   /* 64 */
#define LOG2_NCHUNK 6
#define SPLITK  8      /* gemm4 split */
#define OP_SPLITK 4    /* out_proj split */

typedef short short8 __attribute__((ext_vector_type(8)));
typedef unsigned short ushort8v __attribute__((ext_vector_type(8)));
typedef float f32x4 __attribute__((ext_vector_type(4)));

__device__ __forceinline__ float sigmoidf_(float x) { return 1.f / (1.f + __expf(-x)); }
__device__ __forceinline__ ushort f2bf_bits(float f) {
    __hip_bfloat16 h = __float2bfloat16(f);
    return *(ushort*)&h;
}
__device__ __forceinline__ float bf2f(ushort u) {
    union { unsigned int i; float f; } v;
    v.i = ((unsigned int)u) << 16;
    return v.f;
}
#define LOG2E 1.44269504088896f

// ---------------- prep: 4 weight transposes + LayerNorm, ONE dispatch ----------------
__device__ __forceinline__ void transpose_tile(const float* __restrict__ in,
                                               ushort* __restrict__ out,
                                               int R, int C, int cx, int ry)
{
    __shared__ float tile[64][65];
    int c0 = cx * 64, r0 = ry * 64;
    #pragma unroll
    for (int i = 0; i < 16; ++i) {
        int idx = threadIdx.x + i * 256;
        int r = idx >> 6, c = idx & 63;
        tile[r][c] = (r0 + r < R && c0 + c < C) ? in[(long)(r0 + r) * C + (c0 + c)] : 0.f;
    }
    __syncthreads();
    #pragma unroll
    for (int i = 0; i < 16; ++i) {
        int idx = threadIdx.x + i * 256;
        int cc = idx >> 6, rr = idx & 63;
        if (c0 + cc < C && r0 + rr < R)
            out[(long)(c0 + cc) * R + (r0 + rr)] = f2bf_bits(tile[rr][cc]);
    }
}

__device__ __forceinline__ void ln_row(const float* __restrict__ x,
                                       const float* __restrict__ g,
                                       const float* __restrict__ be,
                                       ushort* __restrict__ hb, int row)
{
    __shared__ float red[8];
    const float4* xr = (const float4*)(x + (long)row * D_MODEL);
    float4 v = xr[threadIdx.x];
    float s1 = v.x + v.y + v.z + v.w;
    float s2 = v.x*v.x + v.y*v.y + v.z*v.z + v.w*v.w;
    for (int off = 32; off >= 1; off >>= 1) {
        s1 += __shfl_down(s1, off);
        s2 += __shfl_down(s2, off);
    }
    int wid = threadIdx.x >> 6;
    if ((threadIdx.x & 63) == 0) { red[wid] = s1; red[4 + wid] = s2; }
    __syncthreads();
    float mu  = (red[0] + red[1] + red[2] + red[3]) * (1.f / D_MODEL);
    float ex2 = (red[4] + red[5] + red[6] + red[7]) * (1.f / D_MODEL);
    float inv = rsqrtf(ex2 - mu * mu + 1e-5f);
    float4 g4 = ((const float4*)g)[threadIdx.x];
    float4 b4 = ((const float4*)be)[threadIdx.x];
    ushort4 o;
    o.x = f2bf_bits((v.x - mu) * inv * g4.x + b4.x);
    o.y = f2bf_bits((v.y - mu) * inv * g4.y + b4.y);
    o.z = f2bf_bits((v.z - mu) * inv * g4.z + b4.z);
    o.w = f2bf_bits((v.w - mu) * inv * g4.w + b4.w);
    *(ushort4*)(hb + (long)row * D_MODEL + threadIdx.x * 4) = o;
}

__global__ __launch_bounds__(256) void prep_kernel(const float* __restrict__ w2,
                                                   ushort* __restrict__ W2T,
                                                   const float* __restrict__ w7,
                                                   ushort* __restrict__ W7T,
                                                   const float* __restrict__ xp,
                                                   ushort* __restrict__ XPT,
                                                   const float* __restrict__ dt,
                                                   ushort* __restrict__ DTT,
                                                   const float* __restrict__ x,
                                                   const float* __restrict__ g,
                                                   const float* __restrict__ be,
                                                   ushort* __restrict__ hb)
{
    int idx = blockIdx.x;
    if (idx < 1024) {
        transpose_tile(w2, W2T, D_MODEL, NPROJ, idx & 63, idx >> 6);
    } else if (idx < 1536) {
        int rel = idx - 1024;
        transpose_tile(w7, W7T, D_INNER, D_MODEL, rel & 15, rel >> 4);
    } else if (idx < 1632) {
        int rel = idx - 1536;
        transpose_tile(xp, XPT, D_INNER, XPJ_N, rel % 3, rel / 3);
    } else if (idx < 1696) {
        int rel = idx - 1632;
        transpose_tile(dt, DTT, DT_RANK, D_INNER, rel & 31, rel >> 5);
    } else {
        ln_row(x, g, be, hb, idx - 1696);
    }
}

// ---------------- bf16 MFMA GEMM 128x128, 2-phase double-buffered pipeline -----------
template <int EPI, int OBF>
__global__ __launch_bounds__(256) void gemm_mfma_kernel(const ushort* __restrict__ A,
                                                        const ushort* __restrict__ Bt,
                                                        const float* __restrict__ bias,
                                                        float* __restrict__ Cf,
                                                        ushort* __restrict__ Cb,
                                                        int M, int N, int K, int lda, int ldb)
{
    long zoff = (long)blockIdx.z;
    A  += zoff * K;
    Bt += zoff * K;
    if (OBF == 0) Cf += zoff * (long)M * N;
    else          Cb += zoff * (long)M * N;
    int lin = blockIdx.y * gridDim.x + blockIdx.x;
    int cpx = (gridDim.x * gridDim.y) >> 3;
    lin = (lin & 7) * cpx + (lin >> 3);
    int bx = lin % gridDim.x, by = lin / gridDim.x;
    __shared__ __align__(16) ushort Al[2][128 * 32];
    __shared__ __align__(16) ushort Bl[2][128 * 32];
    int tid = threadIdx.x;
    int lane = tid & 63;
    int w = tid >> 6, wr = w >> 1, wc = w & 1;
    int m0 = by * 128, n0 = bx * 128;
    f32x4 acc[4][4];
    #pragma unroll
    for (int m = 0; m < 4; ++m)
        #pragma unroll
        for (int n = 0; n < 4; ++n) acc[m][n] = (f32x4){0.f, 0.f, 0.f, 0.f};
    int l15 = lane & 15, kq = lane >> 4;

    auto stage = [&](int buf, int k0) {
        #pragma unroll
        for (int i = 0; i < 2; ++i) {
            int s = i * 256 + tid;
            int row = s >> 2, kg = s & 3;
            int kgl = kg ^ ((row >> 1) & 3);
            __builtin_amdgcn_global_load_lds(
                (const __attribute__((address_space(1))) void*)(A + (long)(m0 + row) * lda + k0 + kgl * 8),
                (__attribute__((address_space(3))) void*)(Al[buf] + s * 8), 16, 0, 0);
            __builtin_amdgcn_global_load_lds(
                (const __attribute__((address_space(1))) void*)(Bt + (long)(n0 + row) * ldb + k0 + kgl * 8),
                (__attribute__((address_space(3))) void*)(Bl[buf] + s * 8), 16, 0, 0);
        }
    };

    stage(0, 0);
    int cur = 0;
    for (int k0 = 0; k0 < K; k0 += 32) {
        if (k0 + 32 < K) {
            stage(cur ^ 1, k0 + 32);
            asm volatile("s_waitcnt vmcnt(4)" ::: "memory");
        } else {
            asm volatile("s_waitcnt vmcnt(0)" ::: "memory");
        }
        __builtin_amdgcn_s_barrier();
        asm volatile("" ::: "memory");
        short8 af[4], bf[4];
        #pragma unroll
        for (int m = 0; m < 4; ++m) {
            int row = wr * 64 + m * 16 + l15;
            af[m] = *(const short8*)&Al[cur][row * 32 + (kq ^ ((row >> 1) & 3)) * 8];
        }
        #pragma unroll
        for (int n = 0; n < 4; ++n) {
            int row = wc * 64 + n * 16 + l15;
            bf[n] = *(const short8*)&Bl[cur][row * 32 + (kq ^ ((row >> 1) & 3)) * 8];
        }
        __builtin_amdgcn_s_setprio(1);
        #pragma unroll
        for (int m = 0; m < 4; ++m)
            #pragma unroll
            for (int n = 0; n < 4; ++n)
                acc[m][n] = __builtin_amdgcn_mfma_f32_16x16x32_bf16(af[m], bf[n], acc[m][n], 0, 0, 0);
        __builtin_amdgcn_s_setprio(0);
        asm volatile("" ::: "memory");
        __builtin_amdgcn_s_barrier();
        asm volatile("" ::: "memory");
        cur ^= 1;
    }
    #pragma unroll
    for (int m = 0; m < 4; ++m) {
        #pragma unroll
        for (int n = 0; n < 4; ++n) {
            #pragma unroll
            for (int r = 0; r < 4; ++r) {
                int row = m0 + wr * 64 + m * 16 + kq * 4 + r;
                int col = n0 + wc * 64 + n * 16 + l15;
                float v = acc[m][n][r];
                if (EPI == 1) {
                    v += bias[col];
                    v = (v > 20.f) ? v : log1pf(__expf(v));
                }
                if (OBF) Cb[(long)row * N + col] = f2bf_bits(v);
                else     Cf[(long)row * N + col] = v;
            }
        }
    }
}

// ---------------- bf16 MFMA GEMM 128x64, 2-phase double-buffered (vmcnt(3)) ----------
template <int EPI, int OBF>
__global__ __launch_bounds__(256) void gemm_mfma64_kernel(const ushort* __restrict__ A,
                                                          const ushort* __restrict__ Bt,
                                                          const float* __restrict__ bias,
                                                          float* __restrict__ Cf,
                                                          ushort* __restrict__ Cb,
                                                          int M, int N, int K)
{
    int lin = blockIdx.y * gridDim.x + blockIdx.x;
    int cpx = (gridDim.x * gridDim.y) >> 3;
    lin = (lin & 7) * cpx + (lin >> 3);
    int bx = lin % gridDim.x, by = lin / gridDim.x;
    __shared__ __align__(16) ushort Al[2][128 * 32];
    __shared__ __align__(16) ushort Bl[2][64 * 32];
    int tid = threadIdx.x;
    int lane = tid & 63;
    int w = tid >> 6, wr = w >> 1, wc = w & 1;
    int m0 = by * 128, n0 = bx * 64;
    f32x4 acc[4][2];
    #pragma unroll
    for (int m = 0; m < 4; ++m)
        #pragma unroll
        for (int n = 0; n < 2; ++n) acc[m][n] = (f32x4){0.f, 0.f, 0.f, 0.f};
    int l15 = lane & 15, kq = lane >> 4;

    auto stage = [&](int buf, int k0) {
        #pragma unroll
        for (int i = 0; i < 2; ++i) {
            int s = i * 256 + tid;
            int row = s >> 2, kg = s & 3;
            int kgl = kg ^ ((row >> 1) & 3);
            __builtin_amdgcn_global_load_lds(
                (const __attribute__((address_space(1))) void*)(A + (long)(m0 + row) * K + k0 + kgl * 8),
                (__attribute__((address_space(3))) void*)(Al[buf] + s * 8), 16, 0, 0);
        }
        {
            int s = tid;
            int row = s >> 2, kg = s & 3;
            int kgl = kg ^ ((row >> 1) & 3);
            __builtin_amdgcn_global_load_lds(
                (const __attribute__((address_space(1))) void*)(Bt + (long)(n0 + row) * K + k0 + kgl * 8),
                (__attribute__((address_space(3))) void*)(Bl[buf] + s * 8), 16, 0, 0);
        }
    };

    stage(0, 0);
    int cur = 0;
    for (int k0 = 0; k0 < K; k0 += 32) {
        if (k0 + 32 < K) {
            stage(cur ^ 1, k0 + 32);
            asm volatile("s_waitcnt vmcnt(3)" ::: "memory");
        } else {
            asm volatile("s_waitcnt vmcnt(0)" ::: "memory");
        }
        __builtin_amdgcn_s_barrier();
        asm volatile("" ::: "memory");
        short8 af[4], bf[2];
        #pragma unroll
        for (int m = 0; m < 4; ++m) {
            int row = wr * 64 + m * 16 + l15;
            af[m] = *(const short8*)&Al[cur][row * 32 + (kq ^ ((row >> 1) & 3)) * 8];
        }
        #pragma unroll
        for (int n = 0; n < 2; ++n) {
            int row = wc * 32 + n * 16 + l15;
            bf[n] = *(const short8*)&Bl[cur][row * 32 + (kq ^ ((row >> 1) & 3)) * 8];
        }
        __builtin_amdgcn_s_setprio(1);
        #pragma unroll
        for (int m = 0; m < 4; ++m)
            #pragma unroll
            for (int n = 0; n < 2; ++n)
                acc[m][n] = __builtin_amdgcn_mfma_f32_16x16x32_bf16(af[m], bf[n], acc[m][n], 0, 0, 0);
        __builtin_amdgcn_s_setprio(0);
        asm volatile("" ::: "memory");
        __builtin_amdgcn_s_barrier();
        asm volatile("" ::: "memory");
        cur ^= 1;
    }
    #pragma unroll
    for (int m = 0; m < 4; ++m) {
        #pragma unroll
        for (int n = 0; n < 2; ++n) {
            #pragma unroll
            for (int r = 0; r < 4; ++r) {
                int row = m0 + wr * 64 + m * 16 + kq * 4 + r;
                int col = n0 + wc * 32 + n * 16 + l15;
                float v = acc[m][n][r];
                if (EPI == 1) {
                    v += bias[col];
                    v = (v > 20.f) ? v : log1pf(__expf(v));
                }
                if (OBF) Cb[(long)row * N + col] = f2bf_bits(v);
                else     Cf[(long)row * N + col] = v;
            }
        }
    }
}

// -------- out_proj split-K reduce (bf16 partials): out = sum_k Ppart[k] + resid ------
__global__ __launch_bounds__(256) void reduce_out_kernel(const ushort* __restrict__ Ppart,
                                                         const float* __restrict__ resid,
                                                         float* __restrict__ out)
{
    long i = (long)blockIdx.x * 256 + threadIdx.x;
    const long STRIDE = (long)NTOK * D_MODEL;
    float4 s;
    ushort4 p0 = ((const ushort4*)Ppart)[i];
    s.x = bf2f(p0.x); s.y = bf2f(p0.y); s.z = bf2f(p0.z); s.w = bf2f(p0.w);
    #pragma unroll
    for (int k = 1; k < OP_SPLITK; ++k) {
        ushort4 pk = ((const ushort4*)(Ppart + k * STRIDE))[i];
        s.x += bf2f(pk.x); s.y += bf2f(pk.y); s.z += bf2f(pk.z); s.w += bf2f(pk.w);
    }
    float4 r = ((const float4*)resid)[i];
    s.x += r.x; s.y += r.y; s.z += r.z; s.w += r.w;
    ((float4*)out)[i] = s;
}

// -------- split-K bf16 MFMA GEMM for xpj (bf16 partials out) --------
__global__ __launch_bounds__(256) void gemm4_mfma_kernel(const ushort* __restrict__ A,
                                                         const ushort* __restrict__ Bt,
                                                         ushort* __restrict__ Ppart,
                                                         int M, int K)
{
    __shared__ __align__(16) ushort Al[64 * 32];
    __shared__ __align__(16) ushort Bl[160 * 32];
    int tid = threadIdx.x;
    int lane = tid & 63;
    int w = tid >> 6, wr = w >> 1, wc = w & 1;
    int sk = blockIdx.x;
    int m0 = blockIdx.y * 64;
    int kbase = sk * (K / SPLITK);
    f32x4 acc[2][5];
    #pragma unroll
    for (int m = 0; m < 2; ++m)
        #pragma unroll
        for (int n = 0; n < 5; ++n) acc[m][n] = (f32x4){0.f, 0.f, 0.f, 0.f};
    int l15 = lane & 15, kq = lane >> 4;

    for (int ks = 0; ks < K / SPLITK; ks += 32) {
        int k0 = kbase + ks;
        {
            int s = tid;
            int row = s >> 2, kg = s & 3;
            int kgl = kg ^ ((row >> 1) & 3);
            __builtin_amdgcn_global_load_lds(
                (const __attribute__((address_space(1))) void*)(A + (long)(m0 + row) * K + k0 + kgl * 8),
                (__attribute__((address_space(3))) void*)(Al + s * 8), 16, 0, 0);
        }
        #pragma unroll
        for (int i = 0; i < 3; ++i) {
            int s = i * 256 + tid;
            if (s < 640) {
                int row = s >> 2, kg = s & 3;
                int kgl = kg ^ ((row >> 1) & 3);
                __builtin_amdgcn_global_load_lds(
                    (const __attribute__((address_space(1))) void*)(Bt + (long)row * K + k0 + kgl * 8),
                    (__attribute__((address_space(3))) void*)(Bl + s * 8), 16, 0, 0);
            }
        }
        __syncthreads();
        short8 af[2], bf[5];
        #pragma unroll
        for (int m = 0; m < 2; ++m) {
            int row = wr * 32 + m * 16 + l15;
            af[m] = *(const short8*)&Al[row * 32 + (kq ^ ((row >> 1) & 3)) * 8];
        }
        #pragma unroll
        for (int n = 0; n < 5; ++n) {
            int row = wc * 80 + n * 16 + l15;
            bf[n] = *(const short8*)&Bl[row * 32 + (kq ^ ((row >> 1) & 3)) * 8];
        }
        #pragma unroll
        for (int m = 0; m < 2; ++m)
            #pragma unroll
            for (int n = 0; n < 5; ++n)
                acc[m][n] = __builtin_amdgcn_mfma_f32_16x16x32_bf16(af[m], bf[n], acc[m][n], 0, 0, 0);
        __syncthreads();
    }
    ushort* P = Ppart + (long)sk * M * XPJ_N;
    #pragma unroll
    for (int m = 0; m < 2; ++m) {
        #pragma unroll
        for (int n = 0; n < 5; ++n) {
            #pragma unroll
            for (int r = 0; r < 4; ++r) {
                int row = m0 + wr * 32 + m * 16 + kq * 4 + r;
                int col = wc * 80 + n * 16 + l15;
                P[(long)row * XPJ_N + col] = f2bf_bits(acc[m][n][r]);
            }
        }
    }
}

// -------- reduce split-K bf16 partials → xpj f32 + dt_r bf16 --------
__global__ __launch_bounds__(256) void reduce_xpj_kernel(const ushort* __restrict__ Ppart,
                                                         float* __restrict__ xpj,
                                                         ushort* __restrict__ dtr)
{
    long i = (long)blockIdx.x * 256 + threadIdx.x;
    float s = 0.f;
    #pragma unroll
    for (int k = 0; k < SPLITK; ++k) s += bf2f(Ppart[k * (long)NTOK * XPJ_N + i]);
    xpj[i] = s;
    int col = (int)(i % XPJ_N);
    long row = i / XPJ_N;
    if (col < DT_RANK) dtr[row * DT_RANK + col] = f2bf_bits(s);
}

// ---------------- depthwise causal conv (width 4) + bias + SiLU; vectorized ushort8 ---
__global__ __launch_bounds__(256) void conv_silu_kernel(const ushort* __restrict__ xzb,
                                                        const float* __restrict__ cw,
                                                        const float* __restrict__ cb,
                                                        ushort* __restrict__ xbb)
{
    long i = (long)blockIdx.x * 256 + threadIdx.x;   // over NTOK*(D_INNER/8)
    int d8 = (int)(i & (D_INNER / 8 - 1));
    long tok = i >> 8;
    int l = (int)(tok & (SEQLEN - 1));
    int d0 = d8 * 8;
    const ushort* base = xzb + tok * NPROJ + d0;
    ushort8v r3 = *(const ushort8v*)base;
    ushort8v r2 = {0,0,0,0,0,0,0,0}, r1 = r2, r0 = r2;
    if (l >= 1) r2 = *(const ushort8v*)(base - NPROJ);
    if (l >= 2) r1 = *(const ushort8v*)(base - 2 * NPROJ);
    if (l >= 3) r0 = *(const ushort8v*)(base - 3 * NPROJ);
    ushort8v o;
    #pragma unroll
    for (int j = 0; j < 8; ++j) {
        int d = d0 + j;
        float4 wv = *(const float4*)&cw[d * 4];
        float acc = cb[d]
                  + bf2f(r0[j]) * wv.x + bf2f(r1[j]) * wv.y
                  + bf2f(r2[j]) * wv.z + bf2f(r3[j]) * wv.w;
        o[j] = f2bf_bits(acc * sigmoidf_(acc));
    }
    *(ushort8v*)(xbb + tok * D_INNER + d0) = o;
}

// ======================= chunked selective scan: 1 lane/channel, CHUNK=16 =============
__global__ __launch_bounds__(256) void scan_partial_kernel(const ushort* __restrict__ deltab,
                                                           const ushort* __restrict__ xbb,
                                                           const float* __restrict__ xpj,
                                                           const float* __restrict__ A_log,
                                                           ushort* __restrict__ Pout,
                                                           ushort* __restrict__ Hout)
{
    __shared__ float bc[CHUNK][16];
    int blk = blockIdx.x;
    int db = blk & 7;
    int c  = (blk >> 3) & (NCHUNK - 1);
    int b  = blk >> (3 + LOG2_NCHUNK);
    int d  = db * 256 + threadIdx.x;
    long tok0 = (long)b * SEQLEN + c * CHUNK;
    {   // stage B rows only (CHUNK x 16 f32), 1 elem/thread
        int t = threadIdx.x >> 4, cc = threadIdx.x & 15;
        bc[t][cc] = xpj[(tok0 + t) * XPJ_N + DT_RANK + cc];
    }
    float a[16], h[16];
    #pragma unroll
    for (int q = 0; q < 4; ++q) {
        float4 al = *(const float4*)&A_log[d * D_STATE + q * 4];
        a[q*4+0] = -__expf(al.x) * LOG2E;
        a[q*4+1] = -__expf(al.y) * LOG2E;
        a[q*4+2] = -__expf(al.z) * LOG2E;
        a[q*4+3] = -__expf(al.w) * LOG2E;
    }
    #pragma unroll
    for (int n = 0; n < 16; ++n) h[n] = 0.f;
    float cum = 0.f;
    const ushort* dp = deltab + tok0 * D_INNER + d;
    const ushort* xp = xbb + tok0 * D_INNER + d;
    __syncthreads();
    #pragma unroll
    for (int t = 0; t < CHUNK; ++t) {
        float dl = bf2f(dp[(long)t * D_INNER]);
        float x  = bf2f(xp[(long)t * D_INNER]);
        float ux = dl * x;
        cum += dl;
        #pragma unroll
        for (int q = 0; q < 4; ++q) {
            float4 Bv = *(const float4*)&bc[t][q * 4];
            h[q*4+0] = exp2f(dl * a[q*4+0]) * h[q*4+0] + ux * Bv.x;
            h[q*4+1] = exp2f(dl * a[q*4+1]) * h[q*4+1] + ux * Bv.y;
            h[q*4+2] = exp2f(dl * a[q*4+2]) * h[q*4+2] + ux * Bv.z;
            h[q*4+3] = exp2f(dl * a[q*4+3]) * h[q*4+3] + ux * Bv.w;
        }
    }
    long chbase = ((long)(b * NCHUNK + c) * D_INNER + d) * D_STATE;
    #pragma unroll
    for (int q = 0; q < 4; ++q) {
        ushort4 pv;
        pv.x = f2bf_bits(exp2f(a[q*4+0] * cum));
        pv.y = f2bf_bits(exp2f(a[q*4+1] * cum));
        pv.z = f2bf_bits(exp2f(a[q*4+2] * cum));
        pv.w = f2bf_bits(exp2f(a[q*4+3] * cum));
        *(ushort4*)&Pout[chbase + q * 4] = pv;
        ushort4 hv;
        hv.x = f2bf_bits(h[q*4+0]); hv.y = f2bf_bits(h[q*4+1]);
        hv.z = f2bf_bits(h[q*4+2]); hv.w = f2bf_bits(h[q*4+3]);
        *(ushort4*)&Hout[chbase + q * 4] = hv;
    }
}

// Serial chunk-prefix scan; 8-deep register prefetch; bf16 in/out, f32 accumulate.
__global__ __launch_bounds__(256) void scan_chunkscan_kernel(const ushort* __restrict__ P,
                                                             const ushort* __restrict__ H,
                                                             ushort* __restrict__ hinit)
{
    long i = (long)blockIdx.x * 256 + threadIdx.x;  // over BATCH*D_INNER*D_STATE
    int n = (int)(i & (D_STATE - 1));
    int d = (int)((i >> 4) & (D_INNER - 1));
    int b = (int)(i >> 15);
    const long cstride = (long)D_INNER * D_STATE;
    long base = ((long)b * NCHUNK) * cstride + (long)d * D_STATE + n;
    float h = 0.f;
    for (int g = 0; g < NCHUNK / 8; ++g) {
        ushort Pr[8], Hr[8];
        #pragma unroll
        for (int j = 0; j < 8; ++j) {
            long o = base + (long)(g * 8 + j) * cstride;
            Pr[j] = P[o];
            Hr[j] = H[o];
        }
        #pragma unroll
        for (int j = 0; j < 8; ++j) {
            long o = base + (long)(g * 8 + j) * cstride;
            hinit[o] = f2bf_bits(h);
            h = bf2f(Pr[j]) * h + bf2f(Hr[j]);
        }
    }
}

__global__ __launch_bounds__(256) void scan_final_kernel(const ushort* __restrict__ deltab,
                                                         const ushort* __restrict__ xbb,
                                                         const float* __restrict__ xpj,
                                                         const ushort* __restrict__ xzb,
                                                         const float* __restrict__ A_log,
                                                         const float* __restrict__ Dp,
                                                         const ushort* __restrict__ hinit,
                                                         ushort* __restrict__ yb)
{
    __shared__ float bc[CHUNK][32];
    int blk = blockIdx.x;
    int db = blk & 7;
    int c  = (blk >> 3) & (NCHUNK - 1);
    int b  = blk >> (3 + LOG2_NCHUNK);
    int d  = db * 256 + threadIdx.x;
    long tok0 = (long)b * SEQLEN + c * CHUNK;
    for (int i = threadIdx.x; i < CHUNK * 32; i += 256) {
        int t = i >> 5, cc = i & 31;
        bc[t][cc] = xpj[(tok0 + t) * XPJ_N + DT_RANK + cc];
    }
    float a[16], h[16];
    #pragma unroll
    for (int q = 0; q < 4; ++q) {
        float4 al = *(const float4*)&A_log[d * D_STATE + q * 4];
        a[q*4+0] = -__expf(al.x) * LOG2E;
        a[q*4+1] = -__expf(al.y) * LOG2E;
        a[q*4+2] = -__expf(al.z) * LOG2E;
        a[q*4+3] = -__expf(al.w) * LOG2E;
    }
    long chbase = ((long)(b * NCHUNK + c) * D_INNER + d) * D_STATE;
    #pragma unroll
    for (int q = 0; q < 4; ++q) {
        ushort4 hv = *(const ushort4*)&hinit[chbase + q * 4];
        h[q*4+0] = bf2f(hv.x); h[q*4+1] = bf2f(hv.y);
        h[q*4+2] = bf2f(hv.z); h[q*4+3] = bf2f(hv.w);
    }
    float dpar = Dp[d];
    const ushort* dp = deltab + tok0 * D_INNER + d;
    const ushort* xp = xbb + tok0 * D_INNER + d;
    const ushort* zp = xzb + tok0 * NPROJ + D_INNER + d;
    ushort* yp = yb + tok0 * D_INNER + d;
    __syncthreads();
    #pragma unroll
    for (int t = 0; t < CHUNK; ++t) {
        float dl = bf2f(dp[(long)t * D_INNER]);
        float x  = bf2f(xp[(long)t * D_INNER]);
        float z  = bf2f(zp[(long)t * NPROJ]);
        float ux = dl * x;
        float y = 0.f;
        #pragma unroll
        for (int q = 0; q < 4; ++q) {
            float4 Bv = *(const float4*)&bc[t][q * 4];
            float4 Cv = *(const float4*)&bc[t][16 + q * 4];
            h[q*4+0] = exp2f(dl * a[q*4+0]) * h[q*4+0] + ux * Bv.x;
            h[q*4+1] = exp2f(dl * a[q*4+1]) * h[q*4+1] + ux * Bv.y;
            h[q*4+2] = exp2f(dl * a[q*4+2]) * h[q*4+2] + ux * Bv.z;
            h[q*4+3] = exp2f(dl * a[q*4+3]) * h[q*4+3] + ux * Bv.w;
            y += h[q*4+0] * Cv.x + h[q*4+1] * Cv.y + h[q*4+2] * Cv.z + h[q*4+3] * Cv.w;
        }
        y += x * dpar;
        yp[(long)t * D_INNER] = f2bf_bits(y * (z * sigmoidf_(z)));
    }
}

extern "C" void kernel_launch(void* const* d_in, const int* in_sizes, int n_in,
                              void* d_out, int out_size, void* d_ws, size_t ws_size,
                              hipStream_t stream) {
    const float* x         = (const float*)d_in[0];
    const float* ln_gamma  = (const float*)d_in[1];
    const float* ln_beta   = (const float*)d_in[2];
    const float* in_proj_w = (const float*)d_in[3];
    const float* conv_w    = (const float*)d_in[4];
    const float* conv_b    = (const float*)d_in[5];
    const float* x_proj_w  = (const float*)d_in[6];
    const float* dt_proj_w = (const float*)d_in[7];
    const float* dt_proj_b = (const float*)d_in[8];
    const float* A_log     = (const float*)d_in[9];
    const float* D_param   = (const float*)d_in[10];
    const float* out_proj_w= (const float*)d_in[11];
    float* out = (float*)d_out;

    // Clean disjoint arena (d_ws ≈ 268 MB; used ≈ 112 MB).
    float* p = (float*)d_ws;
    ushort* hb      = (ushort*)p; p += 1048576;   // [2048][1024] bf16
    ushort* W2T     = (ushort*)p; p += 2097152;   // [4096][1024] bf16
    ushort* W7T     = (ushort*)p; p += 1048576;   // [1024][2048] bf16
    ushort* XPT     = (ushort*)p; p += 163840;    // [160][2048] bf16
    ushort* DTT     = (ushort*)p; p += 131072;    // [2048][128] bf16
    ushort* xz_bf16 = (ushort*)p; p += 4194304;   // [2048 tok][4096] bf16
    ushort* xb_bf16 = (ushort*)p; p += 2097152;   // [tok][2048] bf16
    float*  xpj     = p;          p += 327680;    // [tok][160] f32
    ushort* dtr     = (ushort*)p; p += 131072;    // [tok][128] bf16
    ushort* delta_bf16 = (ushort*)p; p += 2097152;// [tok][2048] bf16
    ushort* Ppart   = (ushort*)p; p += 1310720;   // gemm4 partials [8][2048][160] bf16
    ushort* Pbuf    = (ushort*)p; p += 2097152;   // scan P  [B][64][2048][16] bf16
    ushort* Hbuf    = (ushort*)p; p += 2097152;   // scan H bf16
    ushort* hinit   = (ushort*)p; p += 2097152;   // bf16
    ushort* y_bf16  = (ushort*)p; p += 2097152;   // [tok][2048] bf16
    ushort* PpartO  = (ushort*)p; p += 4194304;   // out_proj partials [4][2048][1024] bf16

    // 0. weight transposes + LayerNorm, one dispatch (independent work overlapped)
    prep_kernel<<<1696 + NTOK, 256, 0, stream>>>(
        in_proj_w, W2T, out_proj_w, W7T, x_proj_w, XPT, dt_proj_w, DTT,
        x, ln_gamma, ln_beta, hb);

    // 2. xz = h @ in_proj_w (MFMA 2-phase, setprio, bf16 out, XCD swizzle)
    gemm_mfma_kernel<0, 1><<<dim3(NPROJ / 128, NTOK / 128), 256, 0, stream>>>(
        hb, W2T, nullptr, nullptr, xz_bf16, NTOK, NPROJ, D_MODEL, D_MODEL, D_MODEL);

    // 3. conv4 + bias + SiLU (vectorized ushort8)
    conv_silu_kernel<<<(NTOK * D_INNER / 8) / 256, 256, 0, stream>>>(
        xz_bf16, conv_w, conv_b, xb_bf16);

    // 4. xpj partials (split-K MFMA, bf16) then reduce → xpj f32 + dtr bf16
    gemm4_mfma_kernel<<<dim3(SPLITK, NTOK / 64), 256, 0, stream>>>(
        xb_bf16, XPT, Ppart, NTOK, D_INNER);
    reduce_xpj_kernel<<<(NTOK * XPJ_N) / 256, 256, 0, stream>>>(Ppart, xpj, dtr);

    // 5. delta = softplus(dt_r @ dt_proj_w + b) (MFMA 128x64 2-phase, bf16 out)
    gemm_mfma64_kernel<1, 1><<<dim3(D_INNER / 64, NTOK / 128), 256, 0, stream>>>(
        dtr, DTT, dt_proj_b, nullptr, delta_bf16, NTOK, D_INNER, DT_RANK);

    // 6. chunked selective scan (1 lane/channel, CHUNK=16, bf16 chunk state)
    scan_partial_kernel<<<BATCH * NCHUNK * 8, 256, 0, stream>>>(
        delta_bf16, xb_bf16, xpj, A_log, Pbuf, Hbuf);
    scan_chunkscan_kernel<<<(BATCH * D_INNER * D_STATE) / 256, 256, 0, stream>>>(
        Pbuf, Hbuf, hinit);
    scan_final_kernel<<<BATCH * NCHUNK * 8, 256, 0, stream>>>(
        delta_bf16, xb_bf16, xpj, xz_bf16, A_log, D_param, hinit, y_bf16);

    // 7. out_proj split-K=4: 2-phase partials (bf16) then fused reduce+residual
    gemm_mfma_kernel<0, 1><<<dim3(D_MODEL / 128, NTOK / 128, OP_SPLITK), 256, 0, stream>>>(
        y_bf16, W7T, nullptr, nullptr, PpartO, NTOK, D_MODEL, D_INNER / OP_SPLITK,
        D_INNER, D_INNER);
    reduce_out_kernel<<<(NTOK * D_MODEL / 4) / 256, 256, 0, stream>>>(PpartO, x, out);
}